// Round 5
// baseline (262.868 us; speedup 1.0000x reference)
//
#include <hip/hip_runtime.h>
#include <math.h>

typedef unsigned short u16;
typedef __attribute__((ext_vector_type(8))) short short8;   // 8 bf16 (4 VGPRs)
typedef __attribute__((ext_vector_type(4))) float f32x4;    // MFMA C/D frag 16x16
typedef __attribute__((ext_vector_type(16))) float f32x16;  // MFMA C/D frag 32x32
typedef __attribute__((ext_vector_type(4))) unsigned int u32x4;

constexpr int Bb = 4, S_LEN = 2048, DMODEL = 1024, NH = 16;
constexpr int MTOT = Bb * S_LEN;  // 8192

// 0.125 (1/sqrt(HD)) * log2(e): folded into Wq so softmax is exp2(sacc).
#define QSCALE 0.18033688011112042f

__device__ __forceinline__ u16 f2bf(float f) {
    union { float f; unsigned u; } v; v.f = f;
    unsigned r = v.u + 0x7FFFu + ((v.u >> 16) & 1u);  // RNE
    return (u16)(r >> 16);
}

__device__ __forceinline__ float exp2_fast(float x) {
#if __has_builtin(__builtin_amdgcn_exp2f)
    return __builtin_amdgcn_exp2f(x);
#else
    float r; asm("v_exp_f32 %0, %1" : "=v"(r) : "v"(x)); return r;
#endif
}

// async global->LDS, 16B per lane. LDS dest = wave-uniform base + lane*16.
__device__ __forceinline__ void load_lds16(const void* g, void* l) {
    __builtin_amdgcn_global_load_lds(
        (const __attribute__((address_space(1))) unsigned int*)g,
        (__attribute__((address_space(3))) unsigned int*)l, 16, 0, 0);
}

// ---------------------------------------------------------------------------
// All 5 input tensors (fp32 — proven by R5-fail/R6-pass A/B) -> bf16, 1 launch.
// Wq (w==0) pre-scaled by QSCALE so attention softmax is exp2(sacc).
// ---------------------------------------------------------------------------
__global__ __launch_bounds__(256)
void cvt_all(const float* __restrict__ x,
             const float* __restrict__ w0, const float* __restrict__ w1,
             const float* __restrict__ w2, const float* __restrict__ w3,
             u16* __restrict__ xb, u16* __restrict__ b0, u16* __restrict__ b1,
             u16* __restrict__ b2, u16* __restrict__ b3)
{
    int gid = blockIdx.x * 256 + threadIdx.x;       // octet index
    constexpr int NXo = (MTOT * DMODEL) / 8;        // 1048576
    constexpr int NWo = (DMODEL * DMODEL) / 8;      // 131072
    const float* s; u16* d; int o;
    float sc = 1.0f;
    if (gid < NXo) { s = x; d = xb; o = gid; }
    else {
        int t = gid - NXo;
        int w = t >> 17;                            // / NWo
        o = t & (NWo - 1);
        s = (w == 0) ? w0 : (w == 1) ? w1 : (w == 2) ? w2 : w3;
        d = (w == 0) ? b0 : (w == 1) ? b1 : (w == 2) ? b2 : b3;
        if (w == 0) sc = QSCALE;
    }
    const float4* sp = (const float4*)(s + (size_t)o * 8);
    float4 a = sp[0], bq = sp[1];
    short8 ov;
    ov[0] = (short)f2bf(a.x * sc);  ov[1] = (short)f2bf(a.y * sc);
    ov[2] = (short)f2bf(a.z * sc);  ov[3] = (short)f2bf(a.w * sc);
    ov[4] = (short)f2bf(bq.x * sc); ov[5] = (short)f2bf(bq.y * sc);
    ov[6] = (short)f2bf(bq.z * sc); ov[7] = (short)f2bf(bq.w * sc);
    *(short8*)(d + (size_t)o * 8) = ov;
}

// ---------------------------------------------------------------------------
// Y[M,N] = X[M,K] * W[N,K]^T   (bf16 in, fp32 acc, bf16 out) — m97 structure.
// ---------------------------------------------------------------------------
__global__ __launch_bounds__(256, 2)
void gemm_bt(const u16* __restrict__ X,
             const u16* __restrict__ W0, const u16* __restrict__ W1, const u16* __restrict__ W2,
             u16* __restrict__ Y0, u16* __restrict__ Y1, u16* __restrict__ Y2,
             int M, int N, int K)
{
    const u16* W = (blockIdx.z == 0) ? W0 : (blockIdx.z == 1) ? W1 : W2;
    u16*       Y = (blockIdx.z == 0) ? Y0 : (blockIdx.z == 1) ? Y1 : Y2;

    __shared__ __align__(16) u16 lA[128 * 64];
    __shared__ __align__(16) u16 lB[128 * 64];

    const int tid  = threadIdx.x;
    const int wave = tid >> 6;
    const int lane = tid & 63;
    const int qd   = lane >> 4;
    const int c    = lane & 15;
    const int tm   = blockIdx.x * 128;
    const int tn   = blockIdx.y * 128;
    const int wm   = (wave >> 1) * 64;
    const int wn   = (wave & 1) * 64;

    f32x4 acc[4][4] = {};

    for (int k0 = 0; k0 < K; k0 += 64) {
        if (k0) __syncthreads();
#pragma unroll
        for (int it = 0; it < 4; ++it) {
            int chunk = it * 256 + tid;
            int row = chunk >> 3, hc = chunk & 7;
            load_lds16(X + (size_t)(tm + row) * K + k0 + hc * 8,
                       (char*)lA + (it * 256 + wave * 64) * 16);
            load_lds16(W + (size_t)(tn + row) * K + k0 + hc * 8,
                       (char*)lB + (it * 256 + wave * 64) * 16);
        }
        __syncthreads();

#pragma unroll
        for (int kk = 0; kk < 64; kk += 32) {
            short8 a[4], b[4];
#pragma unroll
            for (int i = 0; i < 4; ++i) {
                a[i] = *(const short8*)&lA[(wm + i * 16 + c) * 64 + kk + qd * 8];
                b[i] = *(const short8*)&lB[(wn + i * 16 + c) * 64 + kk + qd * 8];
            }
#pragma unroll
            for (int mi = 0; mi < 4; ++mi)
#pragma unroll
                for (int ni = 0; ni < 4; ++ni)
                    acc[mi][ni] = __builtin_amdgcn_mfma_f32_16x16x32_bf16(
                        a[mi], b[ni], acc[mi][ni], 0, 0, 0);
        }
    }

#pragma unroll
    for (int mi = 0; mi < 4; ++mi)
#pragma unroll
        for (int ni = 0; ni < 4; ++ni)
#pragma unroll
            for (int r = 0; r < 4; ++r) {
                int row = tm + wm + mi * 16 + qd * 4 + r;
                int col = tn + wn + ni * 16 + c;
                Y[(size_t)row * N + col] = f2bf(acc[mi][ni][r]);
            }
}

// ---------------------------------------------------------------------------
// Same GEMM, fp32 output (final projection -> d_out, FLOAT32).
// ---------------------------------------------------------------------------
__global__ __launch_bounds__(256, 2)
void gemm_bt_f32(const u16* __restrict__ X, const u16* __restrict__ W,
                 float* __restrict__ Y, int M, int N, int K)
{
    __shared__ __align__(16) u16 lA[128 * 64];
    __shared__ __align__(16) u16 lB[128 * 64];

    const int tid  = threadIdx.x;
    const int wave = tid >> 6;
    const int lane = tid & 63;
    const int qd   = lane >> 4;
    const int c    = lane & 15;
    const int tm   = blockIdx.x * 128;
    const int tn   = blockIdx.y * 128;
    const int wm   = (wave >> 1) * 64;
    const int wn   = (wave & 1) * 64;

    f32x4 acc[4][4] = {};

    for (int k0 = 0; k0 < K; k0 += 64) {
        if (k0) __syncthreads();
#pragma unroll
        for (int it = 0; it < 4; ++it) {
            int chunk = it * 256 + tid;
            int row = chunk >> 3, hc = chunk & 7;
            load_lds16(X + (size_t)(tm + row) * K + k0 + hc * 8,
                       (char*)lA + (it * 256 + wave * 64) * 16);
            load_lds16(W + (size_t)(tn + row) * K + k0 + hc * 8,
                       (char*)lB + (it * 256 + wave * 64) * 16);
        }
        __syncthreads();

#pragma unroll
        for (int kk = 0; kk < 64; kk += 32) {
            short8 a[4], b[4];
#pragma unroll
            for (int i = 0; i < 4; ++i) {
                a[i] = *(const short8*)&lA[(wm + i * 16 + c) * 64 + kk + qd * 8];
                b[i] = *(const short8*)&lB[(wn + i * 16 + c) * 64 + kk + qd * 8];
            }
#pragma unroll
            for (int mi = 0; mi < 4; ++mi)
#pragma unroll
                for (int ni = 0; ni < 4; ++ni)
                    acc[mi][ni] = __builtin_amdgcn_mfma_f32_16x16x32_bf16(
                        a[mi], b[ni], acc[mi][ni], 0, 0, 0);
        }
    }

#pragma unroll
    for (int mi = 0; mi < 4; ++mi)
#pragma unroll
        for (int ni = 0; ni < 4; ++ni)
#pragma unroll
            for (int r = 0; r < 4; ++r) {
                int row = tm + wm + mi * 16 + qd * 4 + r;
                int col = tn + wn + ni * 16 + c;
                Y[(size_t)row * N + col] = acc[mi][ni][r];
            }
}

// ---------------------------------------------------------------------------
// v [B,S,D] -> vt [(b*H+h)*64+hd][S]
// ---------------------------------------------------------------------------
__global__ __launch_bounds__(256)
void transpose_v(const u16* __restrict__ V, u16* __restrict__ VT)
{
    const int sblk = blockIdx.x;
    const int bh   = blockIdx.y;
    const int b = bh >> 4, h = bh & 15;
    __shared__ __align__(16) u16 lT[64][72];

    const int t = threadIdx.x;
#pragma unroll
    for (int it = 0; it < 2; ++it) {
        int chunk = it * 256 + t;
        int si = chunk >> 3, hc = chunk & 7;
        short8 val = *(const short8*)&V[(size_t)(b * S_LEN + sblk * 64 + si) * DMODEL + h * 64 + hc * 8];
        *(short8*)&lT[si][hc * 8] = val;
    }
    __syncthreads();
#pragma unroll
    for (int it = 0; it < 2; ++it) {
        int chunk = it * 256 + t;
        int hd = chunk >> 3, sc = chunk & 7;
        short8 o;
#pragma unroll
        for (int j = 0; j < 8; ++j) o[j] = (short)lT[sc * 8 + j][hd];
        *(short8*)&VT[(size_t)(bh * 64 + hd) * S_LEN + sblk * 64 + sc * 8] = o;
    }
}

// ---------------------------------------------------------------------------
// Flash attention, causal — 8-warp 32x32 in-register softmax (R4) +
// R5: counted-vmcnt double-barrier loop (T4) + setprio around MFMA (T5).
//   __syncthreads per tile compiled to "vmcnt(0); s_barrier" — draining the
//   NEXT tile's prefetch into the critical path (36x per block, ~500-900 cyc
//   each, unhidden at 8 waves/CU). New per-tile protocol:
//     s_barrier            (A: all waves done READING buf[cur^1])
//     issue 2 prefetch loads into buf[cur^1]
//     s_waitcnt vmcnt(2)   (my tile-kt loads landed; prefetch in flight)
//     s_barrier            (B: everyone's tile-kt loads landed)
//     compute buf[cur]
//   Last tile waits vmcnt(0) (nothing left in flight). Barriers sit outside
//   the per-wave mask-skip guard (uniform count, no deadlock). ds_reads of a
//   wave complete before its barrier (results consumed by MFMA -> lgkmcnt).
// ---------------------------------------------------------------------------
__global__ __launch_bounds__(512, 2)
void attention(const u16* __restrict__ Q, const u16* __restrict__ K,
               const u16* __restrict__ VT, u16* __restrict__ CTX)
{
    const int p  = blockIdx.x;     // 0..3 pair index
    const int bh = blockIdx.y;     // 0..63
    const int b = bh >> 4, h = bh & 15;

    __shared__ __align__(16) u16 lK[2][64 * 64];
    __shared__ __align__(16) u16 lV[2][64 * 64];

    const int tid = threadIdx.x, wave = tid >> 6, lane = tid & 63;
    const int l31 = lane & 31, hi = lane >> 5;
    const int wrow = wave * 32;                  // 8 waves x 32 q-rows
    const int srow = tid >> 3, shc = tid & 7;    // 512 lanes cover 64 rows x 8 chunks
    const int shcs = shc ^ (srow & 7);           // pre-swizzled source column chunk
    const int rxk  = l31 & 7;                    // read-side row XOR key (rows l31, 32+l31)
    const size_t kbase = (size_t)(b * S_LEN) * DMODEL + h * 64;
    const size_t vbase = (size_t)(bh * 64) * S_LEN;

#pragma unroll
    for (int phase = 0; phase < 2; ++phase) {
        const int qt = phase ? (7 - p) : p;
        const int q0 = qt * 256;
        const int nkv = 4 * qt + 4;
        const int qrg = q0 + wrow + l31;         // this lane's global q-row

        short8 qf[4];                            // Q B-frags: col=l31, k=hi*8+j
#pragma unroll
        for (int ks = 0; ks < 4; ++ks)
            qf[ks] = *(const short8*)&Q[(size_t)(b * S_LEN + qrg) * DMODEL
                                        + h * 64 + ks * 16 + hi * 8];

        f32x16 oacc0 = {}, oacc1 = {};
        float psum = 0.f;

        __syncthreads();   // phase boundary: previous phase's consumers done (full drain)
        load_lds16(K + kbase + (size_t)srow * DMODEL + shcs * 8,
                   (char*)lK[0] + wave * 1024);
        load_lds16(VT + vbase + (size_t)srow * S_LEN + shcs * 8,
                   (char*)lV[0] + wave * 1024);

        for (int kt = 0; kt < nkv; ++kt) {
            const int cur = kt & 1;
            const int k0 = kt * 64;

            __builtin_amdgcn_s_barrier();        // A: buf[cur^1] readers done
            if (kt + 1 < nkv) {
                const int kn = (kt + 1) * 64;
                load_lds16(K + kbase + (size_t)(kn + srow) * DMODEL + shcs * 8,
                           (char*)lK[cur ^ 1] + wave * 1024);
                load_lds16(VT + vbase + (size_t)srow * S_LEN + kn + shcs * 8,
                           (char*)lV[cur ^ 1] + wave * 1024);
                asm volatile("s_waitcnt vmcnt(2)" ::: "memory");
            } else {
                asm volatile("s_waitcnt vmcnt(0)" ::: "memory");
            }
            __builtin_amdgcn_sched_barrier(0);
            __builtin_amdgcn_s_barrier();        // B: tile-kt loads landed everywhere
            __builtin_amdgcn_sched_barrier(0);

            if (k0 <= q0 + wrow + 31) {          // wave-uniform: not fully masked
                // ---- QK^T (swapped): sacc = S^T ----
                f32x16 s0 = {}, s1 = {};
                __builtin_amdgcn_s_setprio(1);
#pragma unroll
                for (int hs = 0; hs < 4; ++hs) {
                    const int sl = ((hs * 2 + hi) ^ rxk) << 3;
                    short8 kf0 = *(const short8*)&lK[cur][l31 * 64 + sl];
                    short8 kf1 = *(const short8*)&lK[cur][(32 + l31) * 64 + sl];
                    s0 = __builtin_amdgcn_mfma_f32_32x32x16_bf16(kf0, qf[hs], s0, 0, 0, 0);
                    s1 = __builtin_amdgcn_mfma_f32_32x32x16_bf16(kf1, qf[hs], s1, 0, 0, 0);
                }
                __builtin_amdgcn_s_setprio(0);

                // ---- softmax-lite in registers ----
                float pva[16], pvb[16];
                if (k0 + 63 > q0 + wrow) {       // diagonal: apply causal mask
                    const int lim = qrg - k0 - 4 * hi;
#pragma unroll
                    for (int r = 0; r < 16; ++r) {
                        const int ka = (r & 3) + 8 * (r >> 2);
                        pva[r] = (ka > lim)      ? -1.0e38f : s0[r];
                        pvb[r] = (ka + 32 > lim) ? -1.0e38f : s1[r];
                    }
                } else {
#pragma unroll
                    for (int r = 0; r < 16; ++r) { pva[r] = s0[r]; pvb[r] = s1[r]; }
                }
#pragma unroll
                for (int r = 0; r < 16; ++r) {
                    pva[r] = exp2_fast(fminf(pva[r], 86.0f));
                    pvb[r] = exp2_fast(fminf(pvb[r], 86.0f));
                    psum += pva[r] + pvb[r];
                }
                unsigned own0[8], own1[8];
#pragma unroll
                for (int q = 0; q < 8; ++q) {
                    asm("v_cvt_pk_bf16_f32 %0, %1, %2"
                        : "=v"(own0[q]) : "v"(pva[2 * q]), "v"(pva[2 * q + 1]));
                    asm("v_cvt_pk_bf16_f32 %0, %1, %2"
                        : "=v"(own1[q]) : "v"(pvb[2 * q]), "v"(pvb[2 * q + 1]));
                }

                // ---- half-key exchange with lane^32 ----
                unsigned r0a = __shfl_xor((int)(hi ? own0[0] : own0[2]), 32);
                unsigned r0b = __shfl_xor((int)(hi ? own0[1] : own0[3]), 32);
                unsigned r0c = __shfl_xor((int)(hi ? own0[4] : own0[6]), 32);
                unsigned r0d = __shfl_xor((int)(hi ? own0[5] : own0[7]), 32);
                unsigned r1a = __shfl_xor((int)(hi ? own1[0] : own1[2]), 32);
                unsigned r1b = __shfl_xor((int)(hi ? own1[1] : own1[3]), 32);
                unsigned r1c = __shfl_xor((int)(hi ? own1[4] : own1[6]), 32);
                unsigned r1d = __shfl_xor((int)(hi ? own1[5] : own1[7]), 32);
                unsigned o0a = hi ? own0[2] : own0[0];
                unsigned o0b = hi ? own0[3] : own0[1];
                unsigned o0c = hi ? own0[6] : own0[4];
                unsigned o0d = hi ? own0[7] : own0[5];
                unsigned o1a = hi ? own1[2] : own1[0];
                unsigned o1b = hi ? own1[3] : own1[1];
                unsigned o1c = hi ? own1[6] : own1[4];
                unsigned o1d = hi ? own1[7] : own1[5];

                u32x4 w0, w1, w2, w3;
                w0[0] = hi ? r0a : o0a; w0[1] = hi ? r0b : o0b;
                w0[2] = hi ? o0a : r0a; w0[3] = hi ? o0b : r0b;
                w1[0] = hi ? r0c : o0c; w1[1] = hi ? r0d : o0d;
                w1[2] = hi ? o0c : r0c; w1[3] = hi ? o0d : r0d;
                w2[0] = hi ? r1a : o1a; w2[1] = hi ? r1b : o1b;
                w2[2] = hi ? o1a : r1a; w2[3] = hi ? o1b : r1b;
                w3[0] = hi ? r1c : o1c; w3[1] = hi ? r1d : o1d;
                w3[2] = hi ? o1c : r1c; w3[3] = hi ? o1d : r1d;
                short8 pa0 = __builtin_bit_cast(short8, w0);
                short8 pa1 = __builtin_bit_cast(short8, w1);
                short8 pa2 = __builtin_bit_cast(short8, w2);
                short8 pa3 = __builtin_bit_cast(short8, w3);

                // ---- PV: O += P * V ----
                __builtin_amdgcn_s_setprio(1);
#pragma unroll
                for (int ks = 0; ks < 4; ++ks) {
                    const short8 paf = (ks == 0) ? pa0 : (ks == 1) ? pa1
                                     : (ks == 2) ? pa2 : pa3;
                    const int vsl = ((ks * 2 + hi) ^ rxk) << 3;
                    short8 vf0 = *(const short8*)&lV[cur][l31 * 64 + vsl];
                    short8 vf1 = *(const short8*)&lV[cur][(32 + l31) * 64 + vsl];
                    oacc0 = __builtin_amdgcn_mfma_f32_32x32x16_bf16(paf, vf0, oacc0, 0, 0, 0);
                    oacc1 = __builtin_amdgcn_mfma_f32_32x32x16_bf16(paf, vf1, oacc1, 0, 0, 0);
                }
                __builtin_amdgcn_s_setprio(0);
            }
        }

        // ---- epilogue: row sums, normalize, write ----
        float pt = psum + __shfl_xor(psum, 32);   // full row sum for row l31
#pragma unroll
        for (int r = 0; r < 16; ++r) {
            const int orow = (r & 3) + 8 * (r >> 2) + 4 * hi;
            float inv = 1.0f / __shfl(pt, orow);  // sum of output row orow
            const int rowg = q0 + wrow + orow;
            size_t base = (size_t)(b * S_LEN + rowg) * DMODEL + h * 64;
            CTX[base + l31]      = f2bf(oacc0[r] * inv);
            CTX[base + 32 + l31] = f2bf(oacc1[r] * inv);
        }
    }
}

// ---------------------------------------------------------------------------
extern "C" void kernel_launch(void* const* d_in, const int* in_sizes, int n_in,
                              void* d_out, int out_size, void* d_ws, size_t ws_size,
                              hipStream_t stream)
{
    const size_t MB = 1024 * 1024;
    char* ws = (char*)d_ws;
    if (ws_size < 72 * MB + 64) return;

    u16* xb  = (u16*)ws;                  // 0..16MB (vt aliases xb after QKV)
    u16* wb0 = (u16*)(ws + 16 * MB);
    u16* wb1 = (u16*)(ws + 18 * MB);
    u16* wb2 = (u16*)(ws + 20 * MB);
    u16* wb3 = (u16*)(ws + 22 * MB);
    u16* q   = (u16*)(ws + 24 * MB);
    u16* k   = (u16*)(ws + 40 * MB);
    u16* v   = (u16*)(ws + 56 * MB);
    u16* vt  = xb;                        // xb dead after QKV projections
    u16* ctx = v;                         // attention reads vt, not v
    float* out = (float*)d_out;           // output dtype: FLOAT32 (proven R5/R6)

    constexpr int NCVT = (MTOT * DMODEL + 4 * DMODEL * DMODEL) / 8 / 256;  // 6144

    cvt_all<<<NCVT, 256, 0, stream>>>(
        (const float*)d_in[0], (const float*)d_in[1], (const float*)d_in[2],
        (const float*)d_in[3], (const float*)d_in[4], xb, wb0, wb1, wb2, wb3);

    gemm_bt<<<dim3(MTOT / 128, DMODEL / 128, 3), 256, 0, stream>>>(
        xb, wb0, wb1, wb2, q, k, v, MTOT, DMODEL, DMODEL);
    transpose_v<<<dim3(S_LEN / 64, Bb * NH), 256, 0, stream>>>(v, vt);
    attention<<<dim3(4, Bb * NH), 512, 0, stream>>>(q, k, vt, ctx);
    gemm_bt_f32<<<dim3(MTOT / 128, DMODEL / 128, 1), 256, 0, stream>>>(
        ctx, wb3, out, MTOT, DMODEL, DMODEL);
}

// Round 6
// 257.532 us; speedup vs baseline: 1.0207x; 1.0207x over previous
//
#include <hip/hip_runtime.h>
#include <math.h>

typedef unsigned short u16;
typedef __attribute__((ext_vector_type(8))) short short8;   // 8 bf16 (4 VGPRs)
typedef __attribute__((ext_vector_type(4))) float f32x4;    // MFMA C/D frag 16x16
typedef __attribute__((ext_vector_type(16))) float f32x16;  // MFMA C/D frag 32x32
typedef __attribute__((ext_vector_type(4))) unsigned int u32x4;

constexpr int Bb = 4, S_LEN = 2048, DMODEL = 1024, NH = 16;
constexpr int MTOT = Bb * S_LEN;  // 8192

// 0.125 (1/sqrt(HD)) * log2(e): folded into Wq so softmax is exp2(sacc).
#define QSCALE 0.18033688011112042f

__device__ __forceinline__ u16 f2bf(float f) {
    union { float f; unsigned u; } v; v.f = f;
    unsigned r = v.u + 0x7FFFu + ((v.u >> 16) & 1u);  // RNE
    return (u16)(r >> 16);
}

__device__ __forceinline__ float exp2_fast(float x) {
#if __has_builtin(__builtin_amdgcn_exp2f)
    return __builtin_amdgcn_exp2f(x);
#else
    float r; asm("v_exp_f32 %0, %1" : "=v"(r) : "v"(x)); return r;
#endif
}

// async global->LDS, 16B per lane. LDS dest = wave-uniform base + lane*16.
__device__ __forceinline__ void load_lds16(const void* g, void* l) {
    __builtin_amdgcn_global_load_lds(
        (const __attribute__((address_space(1))) unsigned int*)g,
        (__attribute__((address_space(3))) unsigned int*)l, 16, 0, 0);
}

// ---------------------------------------------------------------------------
// All 5 input tensors (fp32 — proven by R5-fail/R6-pass A/B) -> bf16, 1 launch.
// Wq (w==0) pre-scaled by QSCALE so attention softmax is exp2(sacc).
// ---------------------------------------------------------------------------
__global__ __launch_bounds__(256)
void cvt_all(const float* __restrict__ x,
             const float* __restrict__ w0, const float* __restrict__ w1,
             const float* __restrict__ w2, const float* __restrict__ w3,
             u16* __restrict__ xb, u16* __restrict__ b0, u16* __restrict__ b1,
             u16* __restrict__ b2, u16* __restrict__ b3)
{
    int gid = blockIdx.x * 256 + threadIdx.x;       // octet index
    constexpr int NXo = (MTOT * DMODEL) / 8;        // 1048576
    constexpr int NWo = (DMODEL * DMODEL) / 8;      // 131072
    const float* s; u16* d; int o;
    float sc = 1.0f;
    if (gid < NXo) { s = x; d = xb; o = gid; }
    else {
        int t = gid - NXo;
        int w = t >> 17;                            // / NWo
        o = t & (NWo - 1);
        s = (w == 0) ? w0 : (w == 1) ? w1 : (w == 2) ? w2 : w3;
        d = (w == 0) ? b0 : (w == 1) ? b1 : (w == 2) ? b2 : b3;
        if (w == 0) sc = QSCALE;
    }
    const float4* sp = (const float4*)(s + (size_t)o * 8);
    float4 a = sp[0], bq = sp[1];
    short8 ov;
    ov[0] = (short)f2bf(a.x * sc);  ov[1] = (short)f2bf(a.y * sc);
    ov[2] = (short)f2bf(a.z * sc);  ov[3] = (short)f2bf(a.w * sc);
    ov[4] = (short)f2bf(bq.x * sc); ov[5] = (short)f2bf(bq.y * sc);
    ov[6] = (short)f2bf(bq.z * sc); ov[7] = (short)f2bf(bq.w * sc);
    *(short8*)(d + (size_t)o * 8) = ov;
}

// ---------------------------------------------------------------------------
// Y[M,N] = X[M,K] * W[N,K]^T   (bf16 in, fp32 acc, bf16 out) — m97 structure.
// ---------------------------------------------------------------------------
__global__ __launch_bounds__(256, 2)
void gemm_bt(const u16* __restrict__ X,
             const u16* __restrict__ W0, const u16* __restrict__ W1, const u16* __restrict__ W2,
             u16* __restrict__ Y0, u16* __restrict__ Y1, u16* __restrict__ Y2,
             int M, int N, int K)
{
    const u16* W = (blockIdx.z == 0) ? W0 : (blockIdx.z == 1) ? W1 : W2;
    u16*       Y = (blockIdx.z == 0) ? Y0 : (blockIdx.z == 1) ? Y1 : Y2;

    __shared__ __align__(16) u16 lA[128 * 64];
    __shared__ __align__(16) u16 lB[128 * 64];

    const int tid  = threadIdx.x;
    const int wave = tid >> 6;
    const int lane = tid & 63;
    const int qd   = lane >> 4;
    const int c    = lane & 15;
    const int tm   = blockIdx.x * 128;
    const int tn   = blockIdx.y * 128;
    const int wm   = (wave >> 1) * 64;
    const int wn   = (wave & 1) * 64;

    f32x4 acc[4][4] = {};

    for (int k0 = 0; k0 < K; k0 += 64) {
        if (k0) __syncthreads();
#pragma unroll
        for (int it = 0; it < 4; ++it) {
            int chunk = it * 256 + tid;
            int row = chunk >> 3, hc = chunk & 7;
            load_lds16(X + (size_t)(tm + row) * K + k0 + hc * 8,
                       (char*)lA + (it * 256 + wave * 64) * 16);
            load_lds16(W + (size_t)(tn + row) * K + k0 + hc * 8,
                       (char*)lB + (it * 256 + wave * 64) * 16);
        }
        __syncthreads();

#pragma unroll
        for (int kk = 0; kk < 64; kk += 32) {
            short8 a[4], b[4];
#pragma unroll
            for (int i = 0; i < 4; ++i) {
                a[i] = *(const short8*)&lA[(wm + i * 16 + c) * 64 + kk + qd * 8];
                b[i] = *(const short8*)&lB[(wn + i * 16 + c) * 64 + kk + qd * 8];
            }
#pragma unroll
            for (int mi = 0; mi < 4; ++mi)
#pragma unroll
                for (int ni = 0; ni < 4; ++ni)
                    acc[mi][ni] = __builtin_amdgcn_mfma_f32_16x16x32_bf16(
                        a[mi], b[ni], acc[mi][ni], 0, 0, 0);
        }
    }

#pragma unroll
    for (int mi = 0; mi < 4; ++mi)
#pragma unroll
        for (int ni = 0; ni < 4; ++ni)
#pragma unroll
            for (int r = 0; r < 4; ++r) {
                int row = tm + wm + mi * 16 + qd * 4 + r;
                int col = tn + wn + ni * 16 + c;
                Y[(size_t)row * N + col] = f2bf(acc[mi][ni][r]);
            }
}

// ---------------------------------------------------------------------------
// Same GEMM, fp32 output (final projection -> d_out, FLOAT32).
// ---------------------------------------------------------------------------
__global__ __launch_bounds__(256, 2)
void gemm_bt_f32(const u16* __restrict__ X, const u16* __restrict__ W,
                 float* __restrict__ Y, int M, int N, int K)
{
    __shared__ __align__(16) u16 lA[128 * 64];
    __shared__ __align__(16) u16 lB[128 * 64];

    const int tid  = threadIdx.x;
    const int wave = tid >> 6;
    const int lane = tid & 63;
    const int qd   = lane >> 4;
    const int c    = lane & 15;
    const int tm   = blockIdx.x * 128;
    const int tn   = blockIdx.y * 128;
    const int wm   = (wave >> 1) * 64;
    const int wn   = (wave & 1) * 64;

    f32x4 acc[4][4] = {};

    for (int k0 = 0; k0 < K; k0 += 64) {
        if (k0) __syncthreads();
#pragma unroll
        for (int it = 0; it < 4; ++it) {
            int chunk = it * 256 + tid;
            int row = chunk >> 3, hc = chunk & 7;
            load_lds16(X + (size_t)(tm + row) * K + k0 + hc * 8,
                       (char*)lA + (it * 256 + wave * 64) * 16);
            load_lds16(W + (size_t)(tn + row) * K + k0 + hc * 8,
                       (char*)lB + (it * 256 + wave * 64) * 16);
        }
        __syncthreads();

#pragma unroll
        for (int kk = 0; kk < 64; kk += 32) {
            short8 a[4], b[4];
#pragma unroll
            for (int i = 0; i < 4; ++i) {
                a[i] = *(const short8*)&lA[(wm + i * 16 + c) * 64 + kk + qd * 8];
                b[i] = *(const short8*)&lB[(wn + i * 16 + c) * 64 + kk + qd * 8];
            }
#pragma unroll
            for (int mi = 0; mi < 4; ++mi)
#pragma unroll
                for (int ni = 0; ni < 4; ++ni)
                    acc[mi][ni] = __builtin_amdgcn_mfma_f32_16x16x32_bf16(
                        a[mi], b[ni], acc[mi][ni], 0, 0, 0);
        }
    }

#pragma unroll
    for (int mi = 0; mi < 4; ++mi)
#pragma unroll
        for (int ni = 0; ni < 4; ++ni)
#pragma unroll
            for (int r = 0; r < 4; ++r) {
                int row = tm + wm + mi * 16 + qd * 4 + r;
                int col = tn + wn + ni * 16 + c;
                Y[(size_t)row * N + col] = acc[mi][ni][r];
            }
}

// ---------------------------------------------------------------------------
// v [B,S,D] -> vt [(b*H+h)*64+hd][S]
// ---------------------------------------------------------------------------
__global__ __launch_bounds__(256)
void transpose_v(const u16* __restrict__ V, u16* __restrict__ VT)
{
    const int sblk = blockIdx.x;
    const int bh   = blockIdx.y;
    const int b = bh >> 4, h = bh & 15;
    __shared__ __align__(16) u16 lT[64][72];

    const int t = threadIdx.x;
#pragma unroll
    for (int it = 0; it < 2; ++it) {
        int chunk = it * 256 + t;
        int si = chunk >> 3, hc = chunk & 7;
        short8 val = *(const short8*)&V[(size_t)(b * S_LEN + sblk * 64 + si) * DMODEL + h * 64 + hc * 8];
        *(short8*)&lT[si][hc * 8] = val;
    }
    __syncthreads();
#pragma unroll
    for (int it = 0; it < 2; ++it) {
        int chunk = it * 256 + t;
        int hd = chunk >> 3, sc = chunk & 7;
        short8 o;
#pragma unroll
        for (int j = 0; j < 8; ++j) o[j] = (short)lT[sc * 8 + j][hd];
        *(short8*)&VT[(size_t)(bh * 64 + hd) * S_LEN + sblk * 64 + sc * 8] = o;
    }
}

// ---------------------------------------------------------------------------
// Flash attention, causal — 32x32 in-register softmax (R4) at R2's occupancy.
// R6: 256-thread blocks (4 waves x 32 q-rows = 128-row q-tiles), 8 pair-
//   blocks x 64 bh = 512 blocks = 2 INDEPENDENT blocks/CU (16 waves/CU).
//   R4/R5 had grid=256 = 1 block/CU: both waves per SIMD were in the same
//   barrier-locked block (QK together, softmax together) -> zero MFMA/VALU
//   phase diversity, 47% idle. Independent blocks run phase-shifted (m114).
//   Keeps: swapped QK^T 32x32, P in registers (cvt_pk + shfl_xor(32)),
//   counted-vmcnt double-barrier (4 loads/thread/tile -> vmcnt(4)), setprio.
// ---------------------------------------------------------------------------
__global__ __launch_bounds__(256, 2)
void attention(const u16* __restrict__ Q, const u16* __restrict__ K,
               const u16* __restrict__ VT, u16* __restrict__ CTX)
{
    const int p  = blockIdx.x;     // 0..7 pair index
    const int bh = blockIdx.y;     // 0..63
    const int b = bh >> 4, h = bh & 15;

    __shared__ __align__(16) u16 lK[2][64 * 64];
    __shared__ __align__(16) u16 lV[2][64 * 64];

    const int tid = threadIdx.x, wave = tid >> 6, lane = tid & 63;
    const int l31 = lane & 31, hi = lane >> 5;
    const int wrow = wave * 32;                  // 4 waves x 32 q-rows
    const int srow = tid >> 3, shc = tid & 7;    // 256 lanes: 32 rows x 8 chunks / it
    const int shcs = shc ^ (srow & 7);           // pre-swizzled source column chunk
    const int rxk  = l31 & 7;                    // read-side row XOR key
    const size_t kbase = (size_t)(b * S_LEN) * DMODEL + h * 64;
    const size_t vbase = (size_t)(bh * 64) * S_LEN;

#pragma unroll
    for (int phase = 0; phase < 2; ++phase) {
        const int qt = phase ? (15 - p) : p;     // 16 q-tiles of 128 rows
        const int q0 = qt * 128;
        const int nkv = 2 * qt + 2;
        const int qrg = q0 + wrow + l31;         // this lane's global q-row

        short8 qf[4];                            // Q B-frags: col=l31, k=hi*8+j
#pragma unroll
        for (int ks = 0; ks < 4; ++ks)
            qf[ks] = *(const short8*)&Q[(size_t)(b * S_LEN + qrg) * DMODEL
                                        + h * 64 + ks * 16 + hi * 8];

        f32x16 oacc0 = {}, oacc1 = {};
        float psum = 0.f;

        __syncthreads();   // phase boundary: previous phase's consumers done
#pragma unroll
        for (int it = 0; it < 2; ++it) {         // prefetch tile 0 -> buf 0
            load_lds16(K + kbase + (size_t)(it * 32 + srow) * DMODEL + shcs * 8,
                       (char*)lK[0] + (it * 256 + wave * 64) * 16);
            load_lds16(VT + vbase + (size_t)(it * 32 + srow) * S_LEN + shcs * 8,
                       (char*)lV[0] + (it * 256 + wave * 64) * 16);
        }

        for (int kt = 0; kt < nkv; ++kt) {
            const int cur = kt & 1;
            const int k0 = kt * 64;

            __builtin_amdgcn_s_barrier();        // A: buf[cur^1] readers done
            if (kt + 1 < nkv) {
                const int kn = (kt + 1) * 64;
#pragma unroll
                for (int it = 0; it < 2; ++it) {
                    load_lds16(K + kbase + (size_t)(kn + it * 32 + srow) * DMODEL + shcs * 8,
                               (char*)lK[cur ^ 1] + (it * 256 + wave * 64) * 16);
                    load_lds16(VT + vbase + (size_t)(it * 32 + srow) * S_LEN + kn + shcs * 8,
                               (char*)lV[cur ^ 1] + (it * 256 + wave * 64) * 16);
                }
                asm volatile("s_waitcnt vmcnt(4)" ::: "memory");
            } else {
                asm volatile("s_waitcnt vmcnt(0)" ::: "memory");
            }
            __builtin_amdgcn_sched_barrier(0);
            __builtin_amdgcn_s_barrier();        // B: tile-kt loads landed everywhere
            __builtin_amdgcn_sched_barrier(0);

            if (k0 <= q0 + wrow + 31) {          // wave-uniform: not fully masked
                // ---- QK^T (swapped): sacc = S^T ----
                f32x16 s0 = {}, s1 = {};
                __builtin_amdgcn_s_setprio(1);
#pragma unroll
                for (int hs = 0; hs < 4; ++hs) {
                    const int sl = ((hs * 2 + hi) ^ rxk) << 3;
                    short8 kf0 = *(const short8*)&lK[cur][l31 * 64 + sl];
                    short8 kf1 = *(const short8*)&lK[cur][(32 + l31) * 64 + sl];
                    s0 = __builtin_amdgcn_mfma_f32_32x32x16_bf16(kf0, qf[hs], s0, 0, 0, 0);
                    s1 = __builtin_amdgcn_mfma_f32_32x32x16_bf16(kf1, qf[hs], s1, 0, 0, 0);
                }
                __builtin_amdgcn_s_setprio(0);

                // ---- softmax-lite in registers ----
                float pva[16], pvb[16];
                if (k0 + 63 > q0 + wrow) {       // diagonal: apply causal mask
                    const int lim = qrg - k0 - 4 * hi;
#pragma unroll
                    for (int r = 0; r < 16; ++r) {
                        const int ka = (r & 3) + 8 * (r >> 2);
                        pva[r] = (ka > lim)      ? -1.0e38f : s0[r];
                        pvb[r] = (ka + 32 > lim) ? -1.0e38f : s1[r];
                    }
                } else {
#pragma unroll
                    for (int r = 0; r < 16; ++r) { pva[r] = s0[r]; pvb[r] = s1[r]; }
                }
#pragma unroll
                for (int r = 0; r < 16; ++r) {
                    pva[r] = exp2_fast(fminf(pva[r], 86.0f));
                    pvb[r] = exp2_fast(fminf(pvb[r], 86.0f));
                    psum += pva[r] + pvb[r];
                }
                unsigned own0[8], own1[8];
#pragma unroll
                for (int q = 0; q < 8; ++q) {
                    asm("v_cvt_pk_bf16_f32 %0, %1, %2"
                        : "=v"(own0[q]) : "v"(pva[2 * q]), "v"(pva[2 * q + 1]));
                    asm("v_cvt_pk_bf16_f32 %0, %1, %2"
                        : "=v"(own1[q]) : "v"(pvb[2 * q]), "v"(pvb[2 * q + 1]));
                }

                // ---- half-key exchange with lane^32 ----
                unsigned r0a = __shfl_xor((int)(hi ? own0[0] : own0[2]), 32);
                unsigned r0b = __shfl_xor((int)(hi ? own0[1] : own0[3]), 32);
                unsigned r0c = __shfl_xor((int)(hi ? own0[4] : own0[6]), 32);
                unsigned r0d = __shfl_xor((int)(hi ? own0[5] : own0[7]), 32);
                unsigned r1a = __shfl_xor((int)(hi ? own1[0] : own1[2]), 32);
                unsigned r1b = __shfl_xor((int)(hi ? own1[1] : own1[3]), 32);
                unsigned r1c = __shfl_xor((int)(hi ? own1[4] : own1[6]), 32);
                unsigned r1d = __shfl_xor((int)(hi ? own1[5] : own1[7]), 32);
                unsigned o0a = hi ? own0[2] : own0[0];
                unsigned o0b = hi ? own0[3] : own0[1];
                unsigned o0c = hi ? own0[6] : own0[4];
                unsigned o0d = hi ? own0[7] : own0[5];
                unsigned o1a = hi ? own1[2] : own1[0];
                unsigned o1b = hi ? own1[3] : own1[1];
                unsigned o1c = hi ? own1[6] : own1[4];
                unsigned o1d = hi ? own1[7] : own1[5];

                u32x4 w0, w1, w2, w3;
                w0[0] = hi ? r0a : o0a; w0[1] = hi ? r0b : o0b;
                w0[2] = hi ? o0a : r0a; w0[3] = hi ? o0b : r0b;
                w1[0] = hi ? r0c : o0c; w1[1] = hi ? r0d : o0d;
                w1[2] = hi ? o0c : r0c; w1[3] = hi ? o0d : r0d;
                w2[0] = hi ? r1a : o1a; w2[1] = hi ? r1b : o1b;
                w2[2] = hi ? o1a : r1a; w2[3] = hi ? o1b : r1b;
                w3[0] = hi ? r1c : o1c; w3[1] = hi ? r1d : o1d;
                w3[2] = hi ? o1c : r1c; w3[3] = hi ? o1d : r1d;
                short8 pa0 = __builtin_bit_cast(short8, w0);
                short8 pa1 = __builtin_bit_cast(short8, w1);
                short8 pa2 = __builtin_bit_cast(short8, w2);
                short8 pa3 = __builtin_bit_cast(short8, w3);

                // ---- PV: O += P * V ----
                __builtin_amdgcn_s_setprio(1);
#pragma unroll
                for (int ks = 0; ks < 4; ++ks) {
                    const short8 paf = (ks == 0) ? pa0 : (ks == 1) ? pa1
                                     : (ks == 2) ? pa2 : pa3;
                    const int vsl = ((ks * 2 + hi) ^ rxk) << 3;
                    short8 vf0 = *(const short8*)&lV[cur][l31 * 64 + vsl];
                    short8 vf1 = *(const short8*)&lV[cur][(32 + l31) * 64 + vsl];
                    oacc0 = __builtin_amdgcn_mfma_f32_32x32x16_bf16(paf, vf0, oacc0, 0, 0, 0);
                    oacc1 = __builtin_amdgcn_mfma_f32_32x32x16_bf16(paf, vf1, oacc1, 0, 0, 0);
                }
                __builtin_amdgcn_s_setprio(0);
            }
        }

        // ---- epilogue: row sums, normalize, write ----
        float pt = psum + __shfl_xor(psum, 32);   // full row sum for row l31
#pragma unroll
        for (int r = 0; r < 16; ++r) {
            const int orow = (r & 3) + 8 * (r >> 2) + 4 * hi;
            float inv = 1.0f / __shfl(pt, orow);  // sum of output row orow
            const int rowg = q0 + wrow + orow;
            size_t base = (size_t)(b * S_LEN + rowg) * DMODEL + h * 64;
            CTX[base + l31]      = f2bf(oacc0[r] * inv);
            CTX[base + 32 + l31] = f2bf(oacc1[r] * inv);
        }
    }
}

// ---------------------------------------------------------------------------
extern "C" void kernel_launch(void* const* d_in, const int* in_sizes, int n_in,
                              void* d_out, int out_size, void* d_ws, size_t ws_size,
                              hipStream_t stream)
{
    const size_t MB = 1024 * 1024;
    char* ws = (char*)d_ws;
    if (ws_size < 72 * MB + 64) return;

    u16* xb  = (u16*)ws;                  // 0..16MB (vt aliases xb after QKV)
    u16* wb0 = (u16*)(ws + 16 * MB);
    u16* wb1 = (u16*)(ws + 18 * MB);
    u16* wb2 = (u16*)(ws + 20 * MB);
    u16* wb3 = (u16*)(ws + 22 * MB);
    u16* q   = (u16*)(ws + 24 * MB);
    u16* k   = (u16*)(ws + 40 * MB);
    u16* v   = (u16*)(ws + 56 * MB);
    u16* vt  = xb;                        // xb dead after QKV projections
    u16* ctx = v;                         // attention reads vt, not v
    float* out = (float*)d_out;           // output dtype: FLOAT32 (proven R5/R6)

    constexpr int NCVT = (MTOT * DMODEL + 4 * DMODEL * DMODEL) / 8 / 256;  // 6144

    cvt_all<<<NCVT, 256, 0, stream>>>(
        (const float*)d_in[0], (const float*)d_in[1], (const float*)d_in[2],
        (const float*)d_in[3], (const float*)d_in[4], xb, wb0, wb1, wb2, wb3);

    gemm_bt<<<dim3(MTOT / 128, DMODEL / 128, 3), 256, 0, stream>>>(
        xb, wb0, wb1, wb2, q, k, v, MTOT, DMODEL, DMODEL);
    transpose_v<<<dim3(S_LEN / 64, Bb * NH), 256, 0, stream>>>(v, vt);
    attention<<<dim3(8, Bb * NH), 256, 0, stream>>>(q, k, vt, ctx);
    gemm_bt_f32<<<dim3(MTOT / 128, DMODEL / 128, 1), 256, 0, stream>>>(
        ctx, wb3, out, MTOT, DMODEL, DMODEL);
}

// Round 7
// 252.472 us; speedup vs baseline: 1.0412x; 1.0200x over previous
//
#include <hip/hip_runtime.h>
#include <math.h>

typedef unsigned short u16;
typedef __attribute__((ext_vector_type(8))) short short8;   // 8 bf16 (4 VGPRs)
typedef __attribute__((ext_vector_type(4))) float f32x4;    // MFMA C/D frag 16x16
typedef __attribute__((ext_vector_type(16))) float f32x16;  // MFMA C/D frag 32x32
typedef __attribute__((ext_vector_type(4))) unsigned int u32x4;

constexpr int Bb = 4, S_LEN = 2048, DMODEL = 1024, NH = 16;
constexpr int MTOT = Bb * S_LEN;  // 8192

// 0.125 (1/sqrt(HD)) * log2(e): folded into Wq so softmax is exp2(sacc).
#define QSCALE 0.18033688011112042f

__device__ __forceinline__ u16 f2bf(float f) {
    union { float f; unsigned u; } v; v.f = f;
    unsigned r = v.u + 0x7FFFu + ((v.u >> 16) & 1u);  // RNE
    return (u16)(r >> 16);
}

__device__ __forceinline__ float exp2_fast(float x) {
#if __has_builtin(__builtin_amdgcn_exp2f)
    return __builtin_amdgcn_exp2f(x);
#else
    float r; asm("v_exp_f32 %0, %1" : "=v"(r) : "v"(x)); return r;
#endif
}

// async global->LDS, 16B per lane. LDS dest = wave-uniform base + lane*16.
__device__ __forceinline__ void load_lds16(const void* g, void* l) {
    __builtin_amdgcn_global_load_lds(
        (const __attribute__((address_space(1))) unsigned int*)g,
        (__attribute__((address_space(3))) unsigned int*)l, 16, 0, 0);
}

// ---------------------------------------------------------------------------
// All 5 input tensors (fp32 — proven by R5-fail/R6-pass A/B) -> bf16, 1 launch.
// Wq (w==0) pre-scaled by QSCALE so attention softmax is exp2(sacc).
// ---------------------------------------------------------------------------
__global__ __launch_bounds__(256)
void cvt_all(const float* __restrict__ x,
             const float* __restrict__ w0, const float* __restrict__ w1,
             const float* __restrict__ w2, const float* __restrict__ w3,
             u16* __restrict__ xb, u16* __restrict__ b0, u16* __restrict__ b1,
             u16* __restrict__ b2, u16* __restrict__ b3)
{
    int gid = blockIdx.x * 256 + threadIdx.x;       // octet index
    constexpr int NXo = (MTOT * DMODEL) / 8;        // 1048576
    constexpr int NWo = (DMODEL * DMODEL) / 8;      // 131072
    const float* s; u16* d; int o;
    float sc = 1.0f;
    if (gid < NXo) { s = x; d = xb; o = gid; }
    else {
        int t = gid - NXo;
        int w = t >> 17;                            // / NWo
        o = t & (NWo - 1);
        s = (w == 0) ? w0 : (w == 1) ? w1 : (w == 2) ? w2 : w3;
        d = (w == 0) ? b0 : (w == 1) ? b1 : (w == 2) ? b2 : b3;
        if (w == 0) sc = QSCALE;
    }
    const float4* sp = (const float4*)(s + (size_t)o * 8);
    float4 a = sp[0], bq = sp[1];
    short8 ov;
    ov[0] = (short)f2bf(a.x * sc);  ov[1] = (short)f2bf(a.y * sc);
    ov[2] = (short)f2bf(a.z * sc);  ov[3] = (short)f2bf(a.w * sc);
    ov[4] = (short)f2bf(bq.x * sc); ov[5] = (short)f2bf(bq.y * sc);
    ov[6] = (short)f2bf(bq.z * sc); ov[7] = (short)f2bf(bq.w * sc);
    *(short8*)(d + (size_t)o * 8) = ov;
}

// ---------------------------------------------------------------------------
// Y[M,N] = X[M,K] * W[N,K]^T   (bf16 in, fp32 acc, bf16 out) — m97 structure.
// ---------------------------------------------------------------------------
__global__ __launch_bounds__(256, 2)
void gemm_bt(const u16* __restrict__ X,
             const u16* __restrict__ W0, const u16* __restrict__ W1, const u16* __restrict__ W2,
             u16* __restrict__ Y0, u16* __restrict__ Y1, u16* __restrict__ Y2,
             int M, int N, int K)
{
    const u16* W = (blockIdx.z == 0) ? W0 : (blockIdx.z == 1) ? W1 : W2;
    u16*       Y = (blockIdx.z == 0) ? Y0 : (blockIdx.z == 1) ? Y1 : Y2;

    __shared__ __align__(16) u16 lA[128 * 64];
    __shared__ __align__(16) u16 lB[128 * 64];

    const int tid  = threadIdx.x;
    const int wave = tid >> 6;
    const int lane = tid & 63;
    const int qd   = lane >> 4;
    const int c    = lane & 15;
    const int tm   = blockIdx.x * 128;
    const int tn   = blockIdx.y * 128;
    const int wm   = (wave >> 1) * 64;
    const int wn   = (wave & 1) * 64;

    f32x4 acc[4][4] = {};

    for (int k0 = 0; k0 < K; k0 += 64) {
        if (k0) __syncthreads();
#pragma unroll
        for (int it = 0; it < 4; ++it) {
            int chunk = it * 256 + tid;
            int row = chunk >> 3, hc = chunk & 7;
            load_lds16(X + (size_t)(tm + row) * K + k0 + hc * 8,
                       (char*)lA + (it * 256 + wave * 64) * 16);
            load_lds16(W + (size_t)(tn + row) * K + k0 + hc * 8,
                       (char*)lB + (it * 256 + wave * 64) * 16);
        }
        __syncthreads();

#pragma unroll
        for (int kk = 0; kk < 64; kk += 32) {
            short8 a[4], b[4];
#pragma unroll
            for (int i = 0; i < 4; ++i) {
                a[i] = *(const short8*)&lA[(wm + i * 16 + c) * 64 + kk + qd * 8];
                b[i] = *(const short8*)&lB[(wn + i * 16 + c) * 64 + kk + qd * 8];
            }
#pragma unroll
            for (int mi = 0; mi < 4; ++mi)
#pragma unroll
                for (int ni = 0; ni < 4; ++ni)
                    acc[mi][ni] = __builtin_amdgcn_mfma_f32_16x16x32_bf16(
                        a[mi], b[ni], acc[mi][ni], 0, 0, 0);
        }
    }

#pragma unroll
    for (int mi = 0; mi < 4; ++mi)
#pragma unroll
        for (int ni = 0; ni < 4; ++ni)
#pragma unroll
            for (int r = 0; r < 4; ++r) {
                int row = tm + wm + mi * 16 + qd * 4 + r;
                int col = tn + wn + ni * 16 + c;
                Y[(size_t)row * N + col] = f2bf(acc[mi][ni][r]);
            }
}

// ---------------------------------------------------------------------------
// Same GEMM, fp32 output (final projection -> d_out, FLOAT32).
// ---------------------------------------------------------------------------
__global__ __launch_bounds__(256, 2)
void gemm_bt_f32(const u16* __restrict__ X, const u16* __restrict__ W,
                 float* __restrict__ Y, int M, int N, int K)
{
    __shared__ __align__(16) u16 lA[128 * 64];
    __shared__ __align__(16) u16 lB[128 * 64];

    const int tid  = threadIdx.x;
    const int wave = tid >> 6;
    const int lane = tid & 63;
    const int qd   = lane >> 4;
    const int c    = lane & 15;
    const int tm   = blockIdx.x * 128;
    const int tn   = blockIdx.y * 128;
    const int wm   = (wave >> 1) * 64;
    const int wn   = (wave & 1) * 64;

    f32x4 acc[4][4] = {};

    for (int k0 = 0; k0 < K; k0 += 64) {
        if (k0) __syncthreads();
#pragma unroll
        for (int it = 0; it < 4; ++it) {
            int chunk = it * 256 + tid;
            int row = chunk >> 3, hc = chunk & 7;
            load_lds16(X + (size_t)(tm + row) * K + k0 + hc * 8,
                       (char*)lA + (it * 256 + wave * 64) * 16);
            load_lds16(W + (size_t)(tn + row) * K + k0 + hc * 8,
                       (char*)lB + (it * 256 + wave * 64) * 16);
        }
        __syncthreads();

#pragma unroll
        for (int kk = 0; kk < 64; kk += 32) {
            short8 a[4], b[4];
#pragma unroll
            for (int i = 0; i < 4; ++i) {
                a[i] = *(const short8*)&lA[(wm + i * 16 + c) * 64 + kk + qd * 8];
                b[i] = *(const short8*)&lB[(wn + i * 16 + c) * 64 + kk + qd * 8];
            }
#pragma unroll
            for (int mi = 0; mi < 4; ++mi)
#pragma unroll
                for (int ni = 0; ni < 4; ++ni)
                    acc[mi][ni] = __builtin_amdgcn_mfma_f32_16x16x32_bf16(
                        a[mi], b[ni], acc[mi][ni], 0, 0, 0);
        }
    }

#pragma unroll
    for (int mi = 0; mi < 4; ++mi)
#pragma unroll
        for (int ni = 0; ni < 4; ++ni)
#pragma unroll
            for (int r = 0; r < 4; ++r) {
                int row = tm + wm + mi * 16 + qd * 4 + r;
                int col = tn + wn + ni * 16 + c;
                Y[(size_t)row * N + col] = acc[mi][ni][r];
            }
}

// ---------------------------------------------------------------------------
// v [B,S,D] -> vt [(b*H+h)*64+hd][S]
// ---------------------------------------------------------------------------
__global__ __launch_bounds__(256)
void transpose_v(const u16* __restrict__ V, u16* __restrict__ VT)
{
    const int sblk = blockIdx.x;
    const int bh   = blockIdx.y;
    const int b = bh >> 4, h = bh & 15;
    __shared__ __align__(16) u16 lT[64][72];

    const int t = threadIdx.x;
#pragma unroll
    for (int it = 0; it < 2; ++it) {
        int chunk = it * 256 + t;
        int si = chunk >> 3, hc = chunk & 7;
        short8 val = *(const short8*)&V[(size_t)(b * S_LEN + sblk * 64 + si) * DMODEL + h * 64 + hc * 8];
        *(short8*)&lT[si][hc * 8] = val;
    }
    __syncthreads();
#pragma unroll
    for (int it = 0; it < 2; ++it) {
        int chunk = it * 256 + t;
        int hd = chunk >> 3, sc = chunk & 7;
        short8 o;
#pragma unroll
        for (int j = 0; j < 8; ++j) o[j] = (short)lT[sc * 8 + j][hd];
        *(short8*)&VT[(size_t)(bh * 64 + hd) * S_LEN + sblk * 64 + sc * 8] = o;
    }
}

// ---------------------------------------------------------------------------
// Flash attention, causal — 8-warp 32x32 in-register softmax (R4 body).
// R7: occupancy fix done RIGHT. R6's error: occupancy = grid x waves/block,
//   and 512 blocks x 4 waves = 8 waves/CU (same as R4); plus 128-row tiles
//   doubled FETCH (80->146 MB). Now: UNPAIRED 256-row q-tile per block,
//   512 blocks x 8 waves = 4096 waves = 16 waves/CU, 2 independent blocks
//   co-resident per CU (VGPR 76, LDS 32KB -> fits) => MFMA/VALU phase
//   diversity across blocks (m114) AND R4's 80 MB FETCH.
//   Load balance: first 256 blocks are qt 7..4, second 256 are qt 0..3, so
//   CU hosting blocks c and c+256 gets qt pairs summing to 7 (36 KV tiles).
//   Body identical to R5: counted-vmcnt double-barrier, setprio, swapped
//   QK^T, P in registers via cvt_pk + shfl_xor(32).
// ---------------------------------------------------------------------------
__global__ __launch_bounds__(512, 2)
void attention(const u16* __restrict__ Q, const u16* __restrict__ K,
               const u16* __restrict__ VT, u16* __restrict__ CTX)
{
    const int i  = blockIdx.x;               // 0..511
    const int j  = i & 255;
    const int bh = j >> 2;                   // 0..63
    const int t  = j & 3;
    const int qt = (i >> 8) ? t : (7 - t);   // big tiles dispatch first
    const int b = bh >> 4, h = bh & 15;

    __shared__ __align__(16) u16 lK[2][64 * 64];
    __shared__ __align__(16) u16 lV[2][64 * 64];

    const int tid = threadIdx.x, wave = tid >> 6, lane = tid & 63;
    const int l31 = lane & 31, hi = lane >> 5;
    const int wrow = wave * 32;                  // 8 waves x 32 q-rows
    const int srow = tid >> 3, shc = tid & 7;    // 512 lanes cover 64 rows x 8 chunks
    const int shcs = shc ^ (srow & 7);           // pre-swizzled source column chunk
    const int rxk  = l31 & 7;                    // read-side row XOR key
    const size_t kbase = (size_t)(b * S_LEN) * DMODEL + h * 64;
    const size_t vbase = (size_t)(bh * 64) * S_LEN;

    const int q0 = qt * 256;
    const int nkv = 4 * qt + 4;
    const int qrg = q0 + wrow + l31;             // this lane's global q-row

    short8 qf[4];                                // Q B-frags: col=l31, k=hi*8+j
#pragma unroll
    for (int ks = 0; ks < 4; ++ks)
        qf[ks] = *(const short8*)&Q[(size_t)(b * S_LEN + qrg) * DMODEL
                                    + h * 64 + ks * 16 + hi * 8];

    f32x16 oacc0 = {}, oacc1 = {};
    float psum = 0.f;

    load_lds16(K + kbase + (size_t)srow * DMODEL + shcs * 8,
               (char*)lK[0] + wave * 1024);
    load_lds16(VT + vbase + (size_t)srow * S_LEN + shcs * 8,
               (char*)lV[0] + wave * 1024);

    for (int kt = 0; kt < nkv; ++kt) {
        const int cur = kt & 1;
        const int k0 = kt * 64;

        __builtin_amdgcn_s_barrier();        // A: buf[cur^1] readers done
        if (kt + 1 < nkv) {
            const int kn = (kt + 1) * 64;
            load_lds16(K + kbase + (size_t)(kn + srow) * DMODEL + shcs * 8,
                       (char*)lK[cur ^ 1] + wave * 1024);
            load_lds16(VT + vbase + (size_t)srow * S_LEN + kn + shcs * 8,
                       (char*)lV[cur ^ 1] + wave * 1024);
            asm volatile("s_waitcnt vmcnt(2)" ::: "memory");
        } else {
            asm volatile("s_waitcnt vmcnt(0)" ::: "memory");
        }
        __builtin_amdgcn_sched_barrier(0);
        __builtin_amdgcn_s_barrier();        // B: tile-kt loads landed everywhere
        __builtin_amdgcn_sched_barrier(0);

        if (k0 <= q0 + wrow + 31) {          // wave-uniform: not fully masked
            // ---- QK^T (swapped): sacc = S^T ----
            f32x16 s0 = {}, s1 = {};
            __builtin_amdgcn_s_setprio(1);
#pragma unroll
            for (int hs = 0; hs < 4; ++hs) {
                const int sl = ((hs * 2 + hi) ^ rxk) << 3;
                short8 kf0 = *(const short8*)&lK[cur][l31 * 64 + sl];
                short8 kf1 = *(const short8*)&lK[cur][(32 + l31) * 64 + sl];
                s0 = __builtin_amdgcn_mfma_f32_32x32x16_bf16(kf0, qf[hs], s0, 0, 0, 0);
                s1 = __builtin_amdgcn_mfma_f32_32x32x16_bf16(kf1, qf[hs], s1, 0, 0, 0);
            }
            __builtin_amdgcn_s_setprio(0);

            // ---- softmax-lite in registers ----
            float pva[16], pvb[16];
            if (k0 + 63 > q0 + wrow) {       // diagonal: apply causal mask
                const int lim = qrg - k0 - 4 * hi;
#pragma unroll
                for (int r = 0; r < 16; ++r) {
                    const int ka = (r & 3) + 8 * (r >> 2);
                    pva[r] = (ka > lim)      ? -1.0e38f : s0[r];
                    pvb[r] = (ka + 32 > lim) ? -1.0e38f : s1[r];
                }
            } else {
#pragma unroll
                for (int r = 0; r < 16; ++r) { pva[r] = s0[r]; pvb[r] = s1[r]; }
            }
#pragma unroll
            for (int r = 0; r < 16; ++r) {
                pva[r] = exp2_fast(fminf(pva[r], 86.0f));
                pvb[r] = exp2_fast(fminf(pvb[r], 86.0f));
                psum += pva[r] + pvb[r];
            }
            unsigned own0[8], own1[8];
#pragma unroll
            for (int q = 0; q < 8; ++q) {
                asm("v_cvt_pk_bf16_f32 %0, %1, %2"
                    : "=v"(own0[q]) : "v"(pva[2 * q]), "v"(pva[2 * q + 1]));
                asm("v_cvt_pk_bf16_f32 %0, %1, %2"
                    : "=v"(own1[q]) : "v"(pvb[2 * q]), "v"(pvb[2 * q + 1]));
            }

            // ---- half-key exchange with lane^32 ----
            unsigned r0a = __shfl_xor((int)(hi ? own0[0] : own0[2]), 32);
            unsigned r0b = __shfl_xor((int)(hi ? own0[1] : own0[3]), 32);
            unsigned r0c = __shfl_xor((int)(hi ? own0[4] : own0[6]), 32);
            unsigned r0d = __shfl_xor((int)(hi ? own0[5] : own0[7]), 32);
            unsigned r1a = __shfl_xor((int)(hi ? own1[0] : own1[2]), 32);
            unsigned r1b = __shfl_xor((int)(hi ? own1[1] : own1[3]), 32);
            unsigned r1c = __shfl_xor((int)(hi ? own1[4] : own1[6]), 32);
            unsigned r1d = __shfl_xor((int)(hi ? own1[5] : own1[7]), 32);
            unsigned o0a = hi ? own0[2] : own0[0];
            unsigned o0b = hi ? own0[3] : own0[1];
            unsigned o0c = hi ? own0[6] : own0[4];
            unsigned o0d = hi ? own0[7] : own0[5];
            unsigned o1a = hi ? own1[2] : own1[0];
            unsigned o1b = hi ? own1[3] : own1[1];
            unsigned o1c = hi ? own1[6] : own1[4];
            unsigned o1d = hi ? own1[7] : own1[5];

            u32x4 w0, w1, w2, w3;
            w0[0] = hi ? r0a : o0a; w0[1] = hi ? r0b : o0b;
            w0[2] = hi ? o0a : r0a; w0[3] = hi ? o0b : r0b;
            w1[0] = hi ? r0c : o0c; w1[1] = hi ? r0d : o0d;
            w1[2] = hi ? o0c : r0c; w1[3] = hi ? o0d : r0d;
            w2[0] = hi ? r1a : o1a; w2[1] = hi ? r1b : o1b;
            w2[2] = hi ? o1a : r1a; w2[3] = hi ? o1b : r1b;
            w3[0] = hi ? r1c : o1c; w3[1] = hi ? r1d : o1d;
            w3[2] = hi ? o1c : r1c; w3[3] = hi ? o1d : r1d;
            short8 pa0 = __builtin_bit_cast(short8, w0);
            short8 pa1 = __builtin_bit_cast(short8, w1);
            short8 pa2 = __builtin_bit_cast(short8, w2);
            short8 pa3 = __builtin_bit_cast(short8, w3);

            // ---- PV: O += P * V ----
            __builtin_amdgcn_s_setprio(1);
#pragma unroll
            for (int ks = 0; ks < 4; ++ks) {
                const short8 paf = (ks == 0) ? pa0 : (ks == 1) ? pa1
                                 : (ks == 2) ? pa2 : pa3;
                const int vsl = ((ks * 2 + hi) ^ rxk) << 3;
                short8 vf0 = *(const short8*)&lV[cur][l31 * 64 + vsl];
                short8 vf1 = *(const short8*)&lV[cur][(32 + l31) * 64 + vsl];
                oacc0 = __builtin_amdgcn_mfma_f32_32x32x16_bf16(paf, vf0, oacc0, 0, 0, 0);
                oacc1 = __builtin_amdgcn_mfma_f32_32x32x16_bf16(paf, vf1, oacc1, 0, 0, 0);
            }
            __builtin_amdgcn_s_setprio(0);
        }
    }

    // ---- epilogue: row sums, normalize, write ----
    float pt = psum + __shfl_xor(psum, 32);   // full row sum for row l31
#pragma unroll
    for (int r = 0; r < 16; ++r) {
        const int orow = (r & 3) + 8 * (r >> 2) + 4 * hi;
        float inv = 1.0f / __shfl(pt, orow);  // sum of output row orow
        const int rowg = q0 + wrow + orow;
        size_t base = (size_t)(b * S_LEN + rowg) * DMODEL + h * 64;
        CTX[base + l31]      = f2bf(oacc0[r] * inv);
        CTX[base + 32 + l31] = f2bf(oacc1[r] * inv);
    }
}

// ---------------------------------------------------------------------------
extern "C" void kernel_launch(void* const* d_in, const int* in_sizes, int n_in,
                              void* d_out, int out_size, void* d_ws, size_t ws_size,
                              hipStream_t stream)
{
    const size_t MB = 1024 * 1024;
    char* ws = (char*)d_ws;
    if (ws_size < 72 * MB + 64) return;

    u16* xb  = (u16*)ws;                  // 0..16MB (vt aliases xb after QKV)
    u16* wb0 = (u16*)(ws + 16 * MB);
    u16* wb1 = (u16*)(ws + 18 * MB);
    u16* wb2 = (u16*)(ws + 20 * MB);
    u16* wb3 = (u16*)(ws + 22 * MB);
    u16* q   = (u16*)(ws + 24 * MB);
    u16* k   = (u16*)(ws + 40 * MB);
    u16* v   = (u16*)(ws + 56 * MB);
    u16* vt  = xb;                        // xb dead after QKV projections
    u16* ctx = v;                         // attention reads vt, not v
    float* out = (float*)d_out;           // output dtype: FLOAT32 (proven R5/R6)

    constexpr int NCVT = (MTOT * DMODEL + 4 * DMODEL * DMODEL) / 8 / 256;  // 6144

    cvt_all<<<NCVT, 256, 0, stream>>>(
        (const float*)d_in[0], (const float*)d_in[1], (const float*)d_in[2],
        (const float*)d_in[3], (const float*)d_in[4], xb, wb0, wb1, wb2, wb3);

    gemm_bt<<<dim3(MTOT / 128, DMODEL / 128, 3), 256, 0, stream>>>(
        xb, wb0, wb1, wb2, q, k, v, MTOT, DMODEL, DMODEL);
    transpose_v<<<dim3(S_LEN / 64, Bb * NH), 256, 0, stream>>>(v, vt);
    attention<<<512, 512, 0, stream>>>(q, k, vt, ctx);
    gemm_bt_f32<<<dim3(MTOT / 128, DMODEL / 128, 1), 256, 0, stream>>>(
        ctx, wb3, out, MTOT, DMODEL, DMODEL);
}

// Round 8
// 248.772 us; speedup vs baseline: 1.0567x; 1.0149x over previous
//
#include <hip/hip_runtime.h>
#include <math.h>

typedef unsigned short u16;
typedef __attribute__((ext_vector_type(8))) short short8;   // 8 bf16 (4 VGPRs)
typedef __attribute__((ext_vector_type(4))) float f32x4;    // MFMA C/D frag 16x16
typedef __attribute__((ext_vector_type(16))) float f32x16;  // MFMA C/D frag 32x32
typedef __attribute__((ext_vector_type(4))) unsigned int u32x4;

constexpr int Bb = 4, S_LEN = 2048, DMODEL = 1024, NH = 16;
constexpr int MTOT = Bb * S_LEN;  // 8192

// 0.125 (1/sqrt(HD)) * log2(e): folded into Wq so softmax is exp2(sacc).
#define QSCALE 0.18033688011112042f

__device__ __forceinline__ u16 f2bf(float f) {
    union { float f; unsigned u; } v; v.f = f;
    unsigned r = v.u + 0x7FFFu + ((v.u >> 16) & 1u);  // RNE
    return (u16)(r >> 16);
}

__device__ __forceinline__ float exp2_fast(float x) {
#if __has_builtin(__builtin_amdgcn_exp2f)
    return __builtin_amdgcn_exp2f(x);
#else
    float r; asm("v_exp_f32 %0, %1" : "=v"(r) : "v"(x)); return r;
#endif
}

// RNE pack of two f32 -> one dword of 2 bf16 (lo = s0, hi = s1).
__device__ __forceinline__ unsigned pk_bf16(float s0, float s1) {
    unsigned pk;
    asm("v_cvt_pk_bf16_f32 %0, %1, %2" : "=v"(pk) : "v"(s0), "v"(s1));
    return pk;
}

// async global->LDS, 16B per lane. LDS dest = wave-uniform base + lane*16.
__device__ __forceinline__ void load_lds16(const void* g, void* l) {
    __builtin_amdgcn_global_load_lds(
        (const __attribute__((address_space(1))) unsigned int*)g,
        (__attribute__((address_space(3))) unsigned int*)l, 16, 0, 0);
}

// ---------------------------------------------------------------------------
// All 5 input tensors (fp32 — proven by R5-fail/R6-pass A/B) -> bf16, 1 launch.
// Wq (w==0) pre-scaled by QSCALE so attention softmax is exp2(sacc).
// ---------------------------------------------------------------------------
__global__ __launch_bounds__(256)
void cvt_all(const float* __restrict__ x,
             const float* __restrict__ w0, const float* __restrict__ w1,
             const float* __restrict__ w2, const float* __restrict__ w3,
             u16* __restrict__ xb, u16* __restrict__ b0, u16* __restrict__ b1,
             u16* __restrict__ b2, u16* __restrict__ b3)
{
    int gid = blockIdx.x * 256 + threadIdx.x;       // octet index
    constexpr int NXo = (MTOT * DMODEL) / 8;        // 1048576
    constexpr int NWo = (DMODEL * DMODEL) / 8;      // 131072
    const float* s; u16* d; int o;
    float sc = 1.0f;
    if (gid < NXo) { s = x; d = xb; o = gid; }
    else {
        int t = gid - NXo;
        int w = t >> 17;                            // / NWo
        o = t & (NWo - 1);
        s = (w == 0) ? w0 : (w == 1) ? w1 : (w == 2) ? w2 : w3;
        d = (w == 0) ? b0 : (w == 1) ? b1 : (w == 2) ? b2 : b3;
        if (w == 0) sc = QSCALE;
    }
    const float4* sp = (const float4*)(s + (size_t)o * 8);
    float4 a = sp[0], bq = sp[1];
    short8 ov;
    ov[0] = (short)f2bf(a.x * sc);  ov[1] = (short)f2bf(a.y * sc);
    ov[2] = (short)f2bf(a.z * sc);  ov[3] = (short)f2bf(a.w * sc);
    ov[4] = (short)f2bf(bq.x * sc); ov[5] = (short)f2bf(bq.y * sc);
    ov[6] = (short)f2bf(bq.z * sc); ov[7] = (short)f2bf(bq.w * sc);
    *(short8*)(d + (size_t)o * 8) = ov;
}

// ---------------------------------------------------------------------------
// Y[M,N] = X[M,K] * W[N,K]^T   (bf16 in, fp32 acc, bf16 out) — m97 structure.
// R8: epilogue via v_cvt_pk_bf16_f32 pairs (rows r,r+1 share a packed dword;
// lo/hi stored separately) — replaces 256 manual-f2bf VALU ops per lane.
// ---------------------------------------------------------------------------
__global__ __launch_bounds__(256, 2)
void gemm_bt(const u16* __restrict__ X,
             const u16* __restrict__ W0, const u16* __restrict__ W1, const u16* __restrict__ W2,
             u16* __restrict__ Y0, u16* __restrict__ Y1, u16* __restrict__ Y2,
             int M, int N, int K)
{
    const u16* W = (blockIdx.z == 0) ? W0 : (blockIdx.z == 1) ? W1 : W2;
    u16*       Y = (blockIdx.z == 0) ? Y0 : (blockIdx.z == 1) ? Y1 : Y2;

    __shared__ __align__(16) u16 lA[128 * 64];
    __shared__ __align__(16) u16 lB[128 * 64];

    const int tid  = threadIdx.x;
    const int wave = tid >> 6;
    const int lane = tid & 63;
    const int qd   = lane >> 4;
    const int c    = lane & 15;
    const int tm   = blockIdx.x * 128;
    const int tn   = blockIdx.y * 128;
    const int wm   = (wave >> 1) * 64;
    const int wn   = (wave & 1) * 64;

    f32x4 acc[4][4] = {};

    for (int k0 = 0; k0 < K; k0 += 64) {
        if (k0) __syncthreads();
#pragma unroll
        for (int it = 0; it < 4; ++it) {
            int chunk = it * 256 + tid;
            int row = chunk >> 3, hc = chunk & 7;
            load_lds16(X + (size_t)(tm + row) * K + k0 + hc * 8,
                       (char*)lA + (it * 256 + wave * 64) * 16);
            load_lds16(W + (size_t)(tn + row) * K + k0 + hc * 8,
                       (char*)lB + (it * 256 + wave * 64) * 16);
        }
        __syncthreads();

#pragma unroll
        for (int kk = 0; kk < 64; kk += 32) {
            short8 a[4], b[4];
#pragma unroll
            for (int i = 0; i < 4; ++i) {
                a[i] = *(const short8*)&lA[(wm + i * 16 + c) * 64 + kk + qd * 8];
                b[i] = *(const short8*)&lB[(wn + i * 16 + c) * 64 + kk + qd * 8];
            }
#pragma unroll
            for (int mi = 0; mi < 4; ++mi)
#pragma unroll
                for (int ni = 0; ni < 4; ++ni)
                    acc[mi][ni] = __builtin_amdgcn_mfma_f32_16x16x32_bf16(
                        a[mi], b[ni], acc[mi][ni], 0, 0, 0);
        }
    }

#pragma unroll
    for (int mi = 0; mi < 4; ++mi)
#pragma unroll
        for (int ni = 0; ni < 4; ++ni)
#pragma unroll
            for (int r = 0; r < 4; r += 2) {
                unsigned pk = pk_bf16(acc[mi][ni][r], acc[mi][ni][r + 1]);
                int row = tm + wm + mi * 16 + qd * 4 + r;
                int col = tn + wn + ni * 16 + c;
                Y[(size_t)row * N + col]       = (u16)(pk & 0xffffu);
                Y[(size_t)(row + 1) * N + col] = (u16)(pk >> 16);
            }
}

// ---------------------------------------------------------------------------
// Same GEMM, fp32 output (final projection -> d_out, FLOAT32).
// ---------------------------------------------------------------------------
__global__ __launch_bounds__(256, 2)
void gemm_bt_f32(const u16* __restrict__ X, const u16* __restrict__ W,
                 float* __restrict__ Y, int M, int N, int K)
{
    __shared__ __align__(16) u16 lA[128 * 64];
    __shared__ __align__(16) u16 lB[128 * 64];

    const int tid  = threadIdx.x;
    const int wave = tid >> 6;
    const int lane = tid & 63;
    const int qd   = lane >> 4;
    const int c    = lane & 15;
    const int tm   = blockIdx.x * 128;
    const int tn   = blockIdx.y * 128;
    const int wm   = (wave >> 1) * 64;
    const int wn   = (wave & 1) * 64;

    f32x4 acc[4][4] = {};

    for (int k0 = 0; k0 < K; k0 += 64) {
        if (k0) __syncthreads();
#pragma unroll
        for (int it = 0; it < 4; ++it) {
            int chunk = it * 256 + tid;
            int row = chunk >> 3, hc = chunk & 7;
            load_lds16(X + (size_t)(tm + row) * K + k0 + hc * 8,
                       (char*)lA + (it * 256 + wave * 64) * 16);
            load_lds16(W + (size_t)(tn + row) * K + k0 + hc * 8,
                       (char*)lB + (it * 256 + wave * 64) * 16);
        }
        __syncthreads();

#pragma unroll
        for (int kk = 0; kk < 64; kk += 32) {
            short8 a[4], b[4];
#pragma unroll
            for (int i = 0; i < 4; ++i) {
                a[i] = *(const short8*)&lA[(wm + i * 16 + c) * 64 + kk + qd * 8];
                b[i] = *(const short8*)&lB[(wn + i * 16 + c) * 64 + kk + qd * 8];
            }
#pragma unroll
            for (int mi = 0; mi < 4; ++mi)
#pragma unroll
                for (int ni = 0; ni < 4; ++ni)
                    acc[mi][ni] = __builtin_amdgcn_mfma_f32_16x16x32_bf16(
                        a[mi], b[ni], acc[mi][ni], 0, 0, 0);
        }
    }

#pragma unroll
    for (int mi = 0; mi < 4; ++mi)
#pragma unroll
        for (int ni = 0; ni < 4; ++ni)
#pragma unroll
            for (int r = 0; r < 4; ++r) {
                int row = tm + wm + mi * 16 + qd * 4 + r;
                int col = tn + wn + ni * 16 + c;
                Y[(size_t)row * N + col] = acc[mi][ni][r];
            }
}

// ---------------------------------------------------------------------------
// v [B,S,D] -> vt [(b*H+h)*64+hd][S]
// ---------------------------------------------------------------------------
__global__ __launch_bounds__(256)
void transpose_v(const u16* __restrict__ V, u16* __restrict__ VT)
{
    const int sblk = blockIdx.x;
    const int bh   = blockIdx.y;
    const int b = bh >> 4, h = bh & 15;
    __shared__ __align__(16) u16 lT[64][72];

    const int t = threadIdx.x;
#pragma unroll
    for (int it = 0; it < 2; ++it) {
        int chunk = it * 256 + t;
        int si = chunk >> 3, hc = chunk & 7;
        short8 val = *(const short8*)&V[(size_t)(b * S_LEN + sblk * 64 + si) * DMODEL + h * 64 + hc * 8];
        *(short8*)&lT[si][hc * 8] = val;
    }
    __syncthreads();
#pragma unroll
    for (int it = 0; it < 2; ++it) {
        int chunk = it * 256 + t;
        int hd = chunk >> 3, sc = chunk & 7;
        short8 o;
#pragma unroll
        for (int j = 0; j < 8; ++j) o[j] = (short)lT[sc * 8 + j][hd];
        *(short8*)&VT[(size_t)(bh * 64 + hd) * S_LEN + sblk * 64 + sc * 8] = o;
    }
}

// ---------------------------------------------------------------------------
// Flash attention, causal — 8-warp 32x32 in-register softmax (R7 structure).
// R8: half-key exchange via v_permlane32_swap_b32 (gfx950). Derivation
//   (verified bitwise-equal to the R7 shfl+cndmask selects): with
//   a = own[q], b = own[q+2], the swap leaves
//     a' = (lane<32 ? own[q]      : partner's own[q+2])  == frag word w[j]
//     b' = (lane<32 ? partner's own[q] : own[q+2])       == frag word w[j+2]
//   so each frag = {a0',a1',b0',b1'} from two swaps. 8 swaps replace
//   8 ds_bpermute + ~48 v_cndmask per tile (~18% of the VALU budget).
//   Epilogue also packs via v_cvt_pk_bf16_f32 (RNE, same rounding).
// ---------------------------------------------------------------------------
__global__ __launch_bounds__(512, 2)
void attention(const u16* __restrict__ Q, const u16* __restrict__ K,
               const u16* __restrict__ VT, u16* __restrict__ CTX)
{
    const int i  = blockIdx.x;               // 0..511
    const int j  = i & 255;
    const int bh = j >> 2;                   // 0..63
    const int t  = j & 3;
    const int qt = (i >> 8) ? t : (7 - t);   // big tiles dispatch first
    const int b = bh >> 4, h = bh & 15;

    __shared__ __align__(16) u16 lK[2][64 * 64];
    __shared__ __align__(16) u16 lV[2][64 * 64];

    const int tid = threadIdx.x, wave = tid >> 6, lane = tid & 63;
    const int l31 = lane & 31, hi = lane >> 5;
    const int wrow = wave * 32;                  // 8 waves x 32 q-rows
    const int srow = tid >> 3, shc = tid & 7;    // 512 lanes cover 64 rows x 8 chunks
    const int shcs = shc ^ (srow & 7);           // pre-swizzled source column chunk
    const int rxk  = l31 & 7;                    // read-side row XOR key
    const size_t kbase = (size_t)(b * S_LEN) * DMODEL + h * 64;
    const size_t vbase = (size_t)(bh * 64) * S_LEN;

    const int q0 = qt * 256;
    const int nkv = 4 * qt + 4;
    const int qrg = q0 + wrow + l31;             // this lane's global q-row

    short8 qf[4];                                // Q B-frags: col=l31, k=hi*8+j
#pragma unroll
    for (int ks = 0; ks < 4; ++ks)
        qf[ks] = *(const short8*)&Q[(size_t)(b * S_LEN + qrg) * DMODEL
                                    + h * 64 + ks * 16 + hi * 8];

    f32x16 oacc0 = {}, oacc1 = {};
    float psum = 0.f;

    load_lds16(K + kbase + (size_t)srow * DMODEL + shcs * 8,
               (char*)lK[0] + wave * 1024);
    load_lds16(VT + vbase + (size_t)srow * S_LEN + shcs * 8,
               (char*)lV[0] + wave * 1024);

    for (int kt = 0; kt < nkv; ++kt) {
        const int cur = kt & 1;
        const int k0 = kt * 64;

        __builtin_amdgcn_s_barrier();        // A: buf[cur^1] readers done
        if (kt + 1 < nkv) {
            const int kn = (kt + 1) * 64;
            load_lds16(K + kbase + (size_t)(kn + srow) * DMODEL + shcs * 8,
                       (char*)lK[cur ^ 1] + wave * 1024);
            load_lds16(VT + vbase + (size_t)srow * S_LEN + kn + shcs * 8,
                       (char*)lV[cur ^ 1] + wave * 1024);
            asm volatile("s_waitcnt vmcnt(2)" ::: "memory");
        } else {
            asm volatile("s_waitcnt vmcnt(0)" ::: "memory");
        }
        __builtin_amdgcn_sched_barrier(0);
        __builtin_amdgcn_s_barrier();        // B: tile-kt loads landed everywhere
        __builtin_amdgcn_sched_barrier(0);

        if (k0 <= q0 + wrow + 31) {          // wave-uniform: not fully masked
            // ---- QK^T (swapped): sacc = S^T ----
            f32x16 s0 = {}, s1 = {};
            __builtin_amdgcn_s_setprio(1);
#pragma unroll
            for (int hs = 0; hs < 4; ++hs) {
                const int sl = ((hs * 2 + hi) ^ rxk) << 3;
                short8 kf0 = *(const short8*)&lK[cur][l31 * 64 + sl];
                short8 kf1 = *(const short8*)&lK[cur][(32 + l31) * 64 + sl];
                s0 = __builtin_amdgcn_mfma_f32_32x32x16_bf16(kf0, qf[hs], s0, 0, 0, 0);
                s1 = __builtin_amdgcn_mfma_f32_32x32x16_bf16(kf1, qf[hs], s1, 0, 0, 0);
            }
            __builtin_amdgcn_s_setprio(0);

            // ---- softmax-lite in registers ----
            float pva[16], pvb[16];
            if (k0 + 63 > q0 + wrow) {       // diagonal: apply causal mask
                const int lim = qrg - k0 - 4 * hi;
#pragma unroll
                for (int r = 0; r < 16; ++r) {
                    const int ka = (r & 3) + 8 * (r >> 2);
                    pva[r] = (ka > lim)      ? -1.0e38f : s0[r];
                    pvb[r] = (ka + 32 > lim) ? -1.0e38f : s1[r];
                }
            } else {
#pragma unroll
                for (int r = 0; r < 16; ++r) { pva[r] = s0[r]; pvb[r] = s1[r]; }
            }
#pragma unroll
            for (int r = 0; r < 16; ++r) {
                pva[r] = exp2_fast(fminf(pva[r], 86.0f));
                pvb[r] = exp2_fast(fminf(pvb[r], 86.0f));
                psum += pva[r] + pvb[r];
            }
            unsigned own0[8], own1[8];
#pragma unroll
            for (int q = 0; q < 8; ++q) {
                own0[q] = pk_bf16(pva[2 * q], pva[2 * q + 1]);
                own1[q] = pk_bf16(pvb[2 * q], pvb[2 * q + 1]);
            }

            // ---- half-key exchange + PV A-frag assembly via permlane32_swap ----
            // frag(f) words: w0,w1 from swap(own[4f'+0], own[4f'+2]) /
            //                swap(own[4f'+1], own[4f'+3]) outputs.
            short8 paf[4];
#pragma unroll
            for (int f = 0; f < 4; ++f) {
                const unsigned* own = (f < 2) ? own0 : own1;
                const int base = (f & 1) * 4;
                unsigned a0 = own[base + 0], b0 = own[base + 2];
                unsigned a1 = own[base + 1], b1 = own[base + 3];
                asm("v_permlane32_swap_b32 %0, %1" : "+v"(a0), "+v"(b0));
                asm("v_permlane32_swap_b32 %0, %1" : "+v"(a1), "+v"(b1));
                u32x4 w; w[0] = a0; w[1] = a1; w[2] = b0; w[3] = b1;
                paf[f] = __builtin_bit_cast(short8, w);
            }

            // ---- PV: O += P * V ----
            __builtin_amdgcn_s_setprio(1);
#pragma unroll
            for (int ks = 0; ks < 4; ++ks) {
                const int vsl = ((ks * 2 + hi) ^ rxk) << 3;
                short8 vf0 = *(const short8*)&lV[cur][l31 * 64 + vsl];
                short8 vf1 = *(const short8*)&lV[cur][(32 + l31) * 64 + vsl];
                oacc0 = __builtin_amdgcn_mfma_f32_32x32x16_bf16(paf[ks], vf0, oacc0, 0, 0, 0);
                oacc1 = __builtin_amdgcn_mfma_f32_32x32x16_bf16(paf[ks], vf1, oacc1, 0, 0, 0);
            }
            __builtin_amdgcn_s_setprio(0);
        }
    }

    // ---- epilogue: row sums, normalize, write (cvt_pk packed) ----
    float pt = psum + __shfl_xor(psum, 32);   // full row sum for row l31
#pragma unroll
    for (int r = 0; r < 16; ++r) {
        const int orow = (r & 3) + 8 * (r >> 2) + 4 * hi;
        float inv = 1.0f / __shfl(pt, orow);  // sum of output row orow
        const int rowg = q0 + wrow + orow;
        size_t base = (size_t)(b * S_LEN + rowg) * DMODEL + h * 64;
        unsigned pk = pk_bf16(oacc0[r] * inv, oacc1[r] * inv);
        CTX[base + l31]      = (u16)(pk & 0xffffu);
        CTX[base + 32 + l31] = (u16)(pk >> 16);
    }
}

// ---------------------------------------------------------------------------
extern "C" void kernel_launch(void* const* d_in, const int* in_sizes, int n_in,
                              void* d_out, int out_size, void* d_ws, size_t ws_size,
                              hipStream_t stream)
{
    const size_t MB = 1024 * 1024;
    char* ws = (char*)d_ws;
    if (ws_size < 72 * MB + 64) return;

    u16* xb  = (u16*)ws;                  // 0..16MB (vt aliases xb after QKV)
    u16* wb0 = (u16*)(ws + 16 * MB);
    u16* wb1 = (u16*)(ws + 18 * MB);
    u16* wb2 = (u16*)(ws + 20 * MB);
    u16* wb3 = (u16*)(ws + 22 * MB);
    u16* q   = (u16*)(ws + 24 * MB);
    u16* k   = (u16*)(ws + 40 * MB);
    u16* v   = (u16*)(ws + 56 * MB);
    u16* vt  = xb;                        // xb dead after QKV projections
    u16* ctx = v;                         // attention reads vt, not v
    float* out = (float*)d_out;           // output dtype: FLOAT32 (proven R5/R6)

    constexpr int NCVT = (MTOT * DMODEL + 4 * DMODEL * DMODEL) / 8 / 256;  // 6144

    cvt_all<<<NCVT, 256, 0, stream>>>(
        (const float*)d_in[0], (const float*)d_in[1], (const float*)d_in[2],
        (const float*)d_in[3], (const float*)d_in[4], xb, wb0, wb1, wb2, wb3);

    gemm_bt<<<dim3(MTOT / 128, DMODEL / 128, 3), 256, 0, stream>>>(
        xb, wb0, wb1, wb2, q, k, v, MTOT, DMODEL, DMODEL);
    transpose_v<<<dim3(S_LEN / 64, Bb * NH), 256, 0, stream>>>(v, vt);
    attention<<<512, 512, 0, stream>>>(q, k, vt, ctx);
    gemm_bt_f32<<<dim3(MTOT / 128, DMODEL / 128, 1), 256, 0, stream>>>(
        ctx, wb3, out, MTOT, DMODEL, DMODEL);
}

// Round 9
// 245.176 us; speedup vs baseline: 1.0722x; 1.0147x over previous
//
#include <hip/hip_runtime.h>
#include <math.h>

typedef unsigned short u16;
typedef __attribute__((ext_vector_type(8))) short short8;   // 8 bf16 (4 VGPRs)
typedef __attribute__((ext_vector_type(4))) float f32x4;    // MFMA C/D frag 16x16
typedef __attribute__((ext_vector_type(16))) float f32x16;  // MFMA C/D frag 32x32
typedef __attribute__((ext_vector_type(4))) unsigned int u32x4;

constexpr int Bb = 4, S_LEN = 2048, DMODEL = 1024, NH = 16;
constexpr int MTOT = Bb * S_LEN;  // 8192

// 0.125 (1/sqrt(HD)) * log2(e): folded into Wq so softmax is exp2(sacc).
#define QSCALE 0.18033688011112042f

__device__ __forceinline__ u16 f2bf(float f) {
    union { float f; unsigned u; } v; v.f = f;
    unsigned r = v.u + 0x7FFFu + ((v.u >> 16) & 1u);  // RNE
    return (u16)(r >> 16);
}

__device__ __forceinline__ float exp2_fast(float x) {
#if __has_builtin(__builtin_amdgcn_exp2f)
    return __builtin_amdgcn_exp2f(x);
#else
    float r; asm("v_exp_f32 %0, %1" : "=v"(r) : "v"(x)); return r;
#endif
}

// RNE pack of two f32 -> one dword of 2 bf16 (lo = s0, hi = s1).
__device__ __forceinline__ unsigned pk_bf16(float s0, float s1) {
    unsigned pk;
    asm("v_cvt_pk_bf16_f32 %0, %1, %2" : "=v"(pk) : "v"(s0), "v"(s1));
    return pk;
}

// async global->LDS, 16B per lane. LDS dest = wave-uniform base + lane*16.
__device__ __forceinline__ void load_lds16(const void* g, void* l) {
    __builtin_amdgcn_global_load_lds(
        (const __attribute__((address_space(1))) unsigned int*)g,
        (__attribute__((address_space(3))) unsigned int*)l, 16, 0, 0);
}

// ---------------------------------------------------------------------------
// All 5 input tensors (fp32 — proven by R5-fail/R6-pass A/B) -> bf16, 1 launch.
// Wq (w==0) pre-scaled by QSCALE so attention softmax is exp2(sacc).
// ---------------------------------------------------------------------------
__global__ __launch_bounds__(256)
void cvt_all(const float* __restrict__ x,
             const float* __restrict__ w0, const float* __restrict__ w1,
             const float* __restrict__ w2, const float* __restrict__ w3,
             u16* __restrict__ xb, u16* __restrict__ b0, u16* __restrict__ b1,
             u16* __restrict__ b2, u16* __restrict__ b3)
{
    int gid = blockIdx.x * 256 + threadIdx.x;       // octet index
    constexpr int NXo = (MTOT * DMODEL) / 8;        // 1048576
    constexpr int NWo = (DMODEL * DMODEL) / 8;      // 131072
    const float* s; u16* d; int o;
    float sc = 1.0f;
    if (gid < NXo) { s = x; d = xb; o = gid; }
    else {
        int t = gid - NXo;
        int w = t >> 17;                            // / NWo
        o = t & (NWo - 1);
        s = (w == 0) ? w0 : (w == 1) ? w1 : (w == 2) ? w2 : w3;
        d = (w == 0) ? b0 : (w == 1) ? b1 : (w == 2) ? b2 : b3;
        if (w == 0) sc = QSCALE;
    }
    const float4* sp = (const float4*)(s + (size_t)o * 8);
    float4 a = sp[0], bq = sp[1];
    short8 ov;
    ov[0] = (short)f2bf(a.x * sc);  ov[1] = (short)f2bf(a.y * sc);
    ov[2] = (short)f2bf(a.z * sc);  ov[3] = (short)f2bf(a.w * sc);
    ov[4] = (short)f2bf(bq.x * sc); ov[5] = (short)f2bf(bq.y * sc);
    ov[6] = (short)f2bf(bq.z * sc); ov[7] = (short)f2bf(bq.w * sc);
    *(short8*)(d + (size_t)o * 8) = ov;
}

// ---------------------------------------------------------------------------
// Y[M,N] = X[M,K] * W[N,K]^T   (bf16 in, fp32 acc, bf16 out) — m97 structure.
// R9: z==2 (V) writes its output TRANSPOSED directly to VT, fusing the old
//   transpose_v kernel (saves its ~11 us + ~12 us launch gap + 33 MB HBM).
//   Each wave owns a 64x64 quadrant: after one __syncthreads (all waves done
//   reading lA/lB), transpose through the wave's OWN 8 KB LDS slice with XOR
//   swizzle  col' = col ^ ((row<<1)&0x38):
//     write: 16 c-lanes permute within 32 B (8 banks), qd groups offset by
//            16 B -> <=2-way (free, m136);
//     read:  8 sc-groups x 4-bank sets cycling all 32 banks -> conflict-free.
//   Wave-local reads: no second barrier, just lgkmcnt(0).
//   VT store: lanes 0-7 write 8x16B consecutive = 128 B contiguous (same
//   pattern as the old transpose_v write loop).
// ---------------------------------------------------------------------------
__global__ __launch_bounds__(256, 2)
void gemm_bt(const u16* __restrict__ X,
             const u16* __restrict__ W0, const u16* __restrict__ W1, const u16* __restrict__ W2,
             u16* __restrict__ Y0, u16* __restrict__ Y1,
             u16* __restrict__ VT,
             int M, int N, int K)
{
    const u16* W = (blockIdx.z == 0) ? W0 : (blockIdx.z == 1) ? W1 : W2;

    __shared__ __align__(16) u16 lds[2 * 128 * 64];   // lA | lB (contiguous)
    u16* lA = lds;
    u16* lB = lds + 128 * 64;

    const int tid  = threadIdx.x;
    const int wave = tid >> 6;
    const int lane = tid & 63;
    const int qd   = lane >> 4;
    const int c    = lane & 15;
    const int tm   = blockIdx.x * 128;
    const int tn   = blockIdx.y * 128;
    const int wm   = (wave >> 1) * 64;
    const int wn   = (wave & 1) * 64;

    f32x4 acc[4][4] = {};

    for (int k0 = 0; k0 < K; k0 += 64) {
        if (k0) __syncthreads();
#pragma unroll
        for (int it = 0; it < 4; ++it) {
            int chunk = it * 256 + tid;
            int row = chunk >> 3, hc = chunk & 7;
            load_lds16(X + (size_t)(tm + row) * K + k0 + hc * 8,
                       (char*)lA + (it * 256 + wave * 64) * 16);
            load_lds16(W + (size_t)(tn + row) * K + k0 + hc * 8,
                       (char*)lB + (it * 256 + wave * 64) * 16);
        }
        __syncthreads();

#pragma unroll
        for (int kk = 0; kk < 64; kk += 32) {
            short8 a[4], b[4];
#pragma unroll
            for (int i = 0; i < 4; ++i) {
                a[i] = *(const short8*)&lA[(wm + i * 16 + c) * 64 + kk + qd * 8];
                b[i] = *(const short8*)&lB[(wn + i * 16 + c) * 64 + kk + qd * 8];
            }
#pragma unroll
            for (int mi = 0; mi < 4; ++mi)
#pragma unroll
                for (int ni = 0; ni < 4; ++ni)
                    acc[mi][ni] = __builtin_amdgcn_mfma_f32_16x16x32_bf16(
                        a[mi], b[ni], acc[mi][ni], 0, 0, 0);
        }
    }

    if (blockIdx.z != 2) {
        u16* Y = (blockIdx.z == 0) ? Y0 : Y1;
#pragma unroll
        for (int mi = 0; mi < 4; ++mi)
#pragma unroll
            for (int ni = 0; ni < 4; ++ni)
#pragma unroll
                for (int r = 0; r < 4; r += 2) {
                    unsigned pk = pk_bf16(acc[mi][ni][r], acc[mi][ni][r + 1]);
                    int row = tm + wm + mi * 16 + qd * 4 + r;
                    int col = tn + wn + ni * 16 + c;
                    Y[(size_t)row * N + col]       = (u16)(pk & 0xffffu);
                    Y[(size_t)(row + 1) * N + col] = (u16)(pk >> 16);
                }
    } else {
        // ---- fused V-transpose epilogue ----
        __syncthreads();                       // all waves done reading lA/lB
        u16* Tw = lds + wave * 4096;           // this wave's 8 KB slice
#pragma unroll
        for (int mi = 0; mi < 4; ++mi)
#pragma unroll
            for (int ni = 0; ni < 4; ++ni)
#pragma unroll
                for (int r = 0; r < 4; r += 2) {
                    unsigned pk = pk_bf16(acc[mi][ni][r], acc[mi][ni][r + 1]);
                    int r0 = mi * 16 + qd * 4 + r;
                    int cl = ni * 16 + c;
                    Tw[r0 * 64       + (cl ^ ((r0 << 1) & 0x38))]        = (u16)(pk & 0xffffu);
                    Tw[(r0 + 1) * 64 + (cl ^ (((r0 + 1) << 1) & 0x38))]  = (u16)(pk >> 16);
                }
        asm volatile("s_waitcnt lgkmcnt(0)" ::: "memory");  // wave-local order

        const int b2   = tm >> 11;             // batch (tile never crosses b)
        const int smb  = (tm & 2047) + wm;     // s-base of this wave's quadrant
        const int hgl  = (tn + wn) >> 6;       // head (wn multiple of 64)
        const int sc8  = lane & 7;
#pragma unroll
        for (int it = 0; it < 8; ++it) {
            int hd = it * 8 + (lane >> 3);
            short8 o;
#pragma unroll
            for (int jj = 0; jj < 8; ++jj) {
                int rr = sc8 * 8 + jj;
                o[jj] = (short)Tw[rr * 64 + (hd ^ ((rr << 1) & 0x38))];
            }
            *(short8*)&VT[(size_t)((b2 * 16 + hgl) * 64 + hd) * S_LEN + smb + sc8 * 8] = o;
        }
    }
}

// ---------------------------------------------------------------------------
// Same GEMM, fp32 output (final projection -> d_out, FLOAT32).
// ---------------------------------------------------------------------------
__global__ __launch_bounds__(256, 2)
void gemm_bt_f32(const u16* __restrict__ X, const u16* __restrict__ W,
                 float* __restrict__ Y, int M, int N, int K)
{
    __shared__ __align__(16) u16 lA[128 * 64];
    __shared__ __align__(16) u16 lB[128 * 64];

    const int tid  = threadIdx.x;
    const int wave = tid >> 6;
    const int lane = tid & 63;
    const int qd   = lane >> 4;
    const int c    = lane & 15;
    const int tm   = blockIdx.x * 128;
    const int tn   = blockIdx.y * 128;
    const int wm   = (wave >> 1) * 64;
    const int wn   = (wave & 1) * 64;

    f32x4 acc[4][4] = {};

    for (int k0 = 0; k0 < K; k0 += 64) {
        if (k0) __syncthreads();
#pragma unroll
        for (int it = 0; it < 4; ++it) {
            int chunk = it * 256 + tid;
            int row = chunk >> 3, hc = chunk & 7;
            load_lds16(X + (size_t)(tm + row) * K + k0 + hc * 8,
                       (char*)lA + (it * 256 + wave * 64) * 16);
            load_lds16(W + (size_t)(tn + row) * K + k0 + hc * 8,
                       (char*)lB + (it * 256 + wave * 64) * 16);
        }
        __syncthreads();

#pragma unroll
        for (int kk = 0; kk < 64; kk += 32) {
            short8 a[4], b[4];
#pragma unroll
            for (int i = 0; i < 4; ++i) {
                a[i] = *(const short8*)&lA[(wm + i * 16 + c) * 64 + kk + qd * 8];
                b[i] = *(const short8*)&lB[(wn + i * 16 + c) * 64 + kk + qd * 8];
            }
#pragma unroll
            for (int mi = 0; mi < 4; ++mi)
#pragma unroll
                for (int ni = 0; ni < 4; ++ni)
                    acc[mi][ni] = __builtin_amdgcn_mfma_f32_16x16x32_bf16(
                        a[mi], b[ni], acc[mi][ni], 0, 0, 0);
        }
    }

#pragma unroll
    for (int mi = 0; mi < 4; ++mi)
#pragma unroll
        for (int ni = 0; ni < 4; ++ni)
#pragma unroll
            for (int r = 0; r < 4; ++r) {
                int row = tm + wm + mi * 16 + qd * 4 + r;
                int col = tn + wn + ni * 16 + c;
                Y[(size_t)row * N + col] = acc[mi][ni][r];
            }
}

// ---------------------------------------------------------------------------
// Flash attention, causal — 8-warp 32x32 in-register softmax (R8 body,
// unchanged: permlane32_swap exchange, cvt_pk packing, counted vmcnt,
// setprio, 256-row q-tiles, big-tiles-first dispatch).
// ---------------------------------------------------------------------------
__global__ __launch_bounds__(512, 2)
void attention(const u16* __restrict__ Q, const u16* __restrict__ K,
               const u16* __restrict__ VT, u16* __restrict__ CTX)
{
    const int i  = blockIdx.x;               // 0..511
    const int j  = i & 255;
    const int bh = j >> 2;                   // 0..63
    const int t  = j & 3;
    const int qt = (i >> 8) ? t : (7 - t);   // big tiles dispatch first
    const int b = bh >> 4, h = bh & 15;

    __shared__ __align__(16) u16 lK[2][64 * 64];
    __shared__ __align__(16) u16 lV[2][64 * 64];

    const int tid = threadIdx.x, wave = tid >> 6, lane = tid & 63;
    const int l31 = lane & 31, hi = lane >> 5;
    const int wrow = wave * 32;                  // 8 waves x 32 q-rows
    const int srow = tid >> 3, shc = tid & 7;    // 512 lanes cover 64 rows x 8 chunks
    const int shcs = shc ^ (srow & 7);           // pre-swizzled source column chunk
    const int rxk  = l31 & 7;                    // read-side row XOR key
    const size_t kbase = (size_t)(b * S_LEN) * DMODEL + h * 64;
    const size_t vbase = (size_t)(bh * 64) * S_LEN;

    const int q0 = qt * 256;
    const int nkv = 4 * qt + 4;
    const int qrg = q0 + wrow + l31;             // this lane's global q-row

    short8 qf[4];                                // Q B-frags: col=l31, k=hi*8+j
#pragma unroll
    for (int ks = 0; ks < 4; ++ks)
        qf[ks] = *(const short8*)&Q[(size_t)(b * S_LEN + qrg) * DMODEL
                                    + h * 64 + ks * 16 + hi * 8];

    f32x16 oacc0 = {}, oacc1 = {};
    float psum = 0.f;

    load_lds16(K + kbase + (size_t)srow * DMODEL + shcs * 8,
               (char*)lK[0] + wave * 1024);
    load_lds16(VT + vbase + (size_t)srow * S_LEN + shcs * 8,
               (char*)lV[0] + wave * 1024);

    for (int kt = 0; kt < nkv; ++kt) {
        const int cur = kt & 1;
        const int k0 = kt * 64;

        __builtin_amdgcn_s_barrier();        // A: buf[cur^1] readers done
        if (kt + 1 < nkv) {
            const int kn = (kt + 1) * 64;
            load_lds16(K + kbase + (size_t)(kn + srow) * DMODEL + shcs * 8,
                       (char*)lK[cur ^ 1] + wave * 1024);
            load_lds16(VT + vbase + (size_t)srow * S_LEN + kn + shcs * 8,
                       (char*)lV[cur ^ 1] + wave * 1024);
            asm volatile("s_waitcnt vmcnt(2)" ::: "memory");
        } else {
            asm volatile("s_waitcnt vmcnt(0)" ::: "memory");
        }
        __builtin_amdgcn_sched_barrier(0);
        __builtin_amdgcn_s_barrier();        // B: tile-kt loads landed everywhere
        __builtin_amdgcn_sched_barrier(0);

        if (k0 <= q0 + wrow + 31) {          // wave-uniform: not fully masked
            // ---- QK^T (swapped): sacc = S^T ----
            f32x16 s0 = {}, s1 = {};
            __builtin_amdgcn_s_setprio(1);
#pragma unroll
            for (int hs = 0; hs < 4; ++hs) {
                const int sl = ((hs * 2 + hi) ^ rxk) << 3;
                short8 kf0 = *(const short8*)&lK[cur][l31 * 64 + sl];
                short8 kf1 = *(const short8*)&lK[cur][(32 + l31) * 64 + sl];
                s0 = __builtin_amdgcn_mfma_f32_32x32x16_bf16(kf0, qf[hs], s0, 0, 0, 0);
                s1 = __builtin_amdgcn_mfma_f32_32x32x16_bf16(kf1, qf[hs], s1, 0, 0, 0);
            }
            __builtin_amdgcn_s_setprio(0);

            // ---- softmax-lite in registers ----
            float pva[16], pvb[16];
            if (k0 + 63 > q0 + wrow) {       // diagonal: apply causal mask
                const int lim = qrg - k0 - 4 * hi;
#pragma unroll
                for (int r = 0; r < 16; ++r) {
                    const int ka = (r & 3) + 8 * (r >> 2);
                    pva[r] = (ka > lim)      ? -1.0e38f : s0[r];
                    pvb[r] = (ka + 32 > lim) ? -1.0e38f : s1[r];
                }
            } else {
#pragma unroll
                for (int r = 0; r < 16; ++r) { pva[r] = s0[r]; pvb[r] = s1[r]; }
            }
#pragma unroll
            for (int r = 0; r < 16; ++r) {
                pva[r] = exp2_fast(fminf(pva[r], 86.0f));
                pvb[r] = exp2_fast(fminf(pvb[r], 86.0f));
                psum += pva[r] + pvb[r];
            }
            unsigned own0[8], own1[8];
#pragma unroll
            for (int q = 0; q < 8; ++q) {
                own0[q] = pk_bf16(pva[2 * q], pva[2 * q + 1]);
                own1[q] = pk_bf16(pvb[2 * q], pvb[2 * q + 1]);
            }

            // ---- half-key exchange + PV A-frag assembly via permlane32_swap ----
            short8 paf[4];
#pragma unroll
            for (int f = 0; f < 4; ++f) {
                const unsigned* own = (f < 2) ? own0 : own1;
                const int base = (f & 1) * 4;
                unsigned a0 = own[base + 0], b0 = own[base + 2];
                unsigned a1 = own[base + 1], b1 = own[base + 3];
                asm("v_permlane32_swap_b32 %0, %1" : "+v"(a0), "+v"(b0));
                asm("v_permlane32_swap_b32 %0, %1" : "+v"(a1), "+v"(b1));
                u32x4 w; w[0] = a0; w[1] = a1; w[2] = b0; w[3] = b1;
                paf[f] = __builtin_bit_cast(short8, w);
            }

            // ---- PV: O += P * V ----
            __builtin_amdgcn_s_setprio(1);
#pragma unroll
            for (int ks = 0; ks < 4; ++ks) {
                const int vsl = ((ks * 2 + hi) ^ rxk) << 3;
                short8 vf0 = *(const short8*)&lV[cur][l31 * 64 + vsl];
                short8 vf1 = *(const short8*)&lV[cur][(32 + l31) * 64 + vsl];
                oacc0 = __builtin_amdgcn_mfma_f32_32x32x16_bf16(paf[ks], vf0, oacc0, 0, 0, 0);
                oacc1 = __builtin_amdgcn_mfma_f32_32x32x16_bf16(paf[ks], vf1, oacc1, 0, 0, 0);
            }
            __builtin_amdgcn_s_setprio(0);
        }
    }

    // ---- epilogue: row sums, normalize, write (cvt_pk packed) ----
    float pt = psum + __shfl_xor(psum, 32);   // full row sum for row l31
#pragma unroll
    for (int r = 0; r < 16; ++r) {
        const int orow = (r & 3) + 8 * (r >> 2) + 4 * hi;
        float inv = 1.0f / __shfl(pt, orow);  // sum of output row orow
        const int rowg = q0 + wrow + orow;
        size_t base = (size_t)(b * S_LEN + rowg) * DMODEL + h * 64;
        unsigned pk = pk_bf16(oacc0[r] * inv, oacc1[r] * inv);
        CTX[base + l31]      = (u16)(pk & 0xffffu);
        CTX[base + 32 + l31] = (u16)(pk >> 16);
    }
}

// ---------------------------------------------------------------------------
extern "C" void kernel_launch(void* const* d_in, const int* in_sizes, int n_in,
                              void* d_out, int out_size, void* d_ws, size_t ws_size,
                              hipStream_t stream)
{
    const size_t MB = 1024 * 1024;
    char* ws = (char*)d_ws;
    if (ws_size < 72 * MB + 64) return;

    u16* xb  = (u16*)ws;                  // 0..16MB (X input; dead after QKV)
    u16* wb0 = (u16*)(ws + 16 * MB);
    u16* wb1 = (u16*)(ws + 18 * MB);
    u16* wb2 = (u16*)(ws + 20 * MB);
    u16* wb3 = (u16*)(ws + 22 * MB);
    u16* q   = (u16*)(ws + 24 * MB);
    u16* k   = (u16*)(ws + 40 * MB);
    u16* vt  = (u16*)(ws + 56 * MB);      // V written TRANSPOSED by gemm_bt z==2
    u16* ctx = xb;                        // xb dead after QKV projections
    float* out = (float*)d_out;           // output dtype: FLOAT32 (proven R5/R6)

    constexpr int NCVT = (MTOT * DMODEL + 4 * DMODEL * DMODEL) / 8 / 256;  // 6144

    cvt_all<<<NCVT, 256, 0, stream>>>(
        (const float*)d_in[0], (const float*)d_in[1], (const float*)d_in[2],
        (const float*)d_in[3], (const float*)d_in[4], xb, wb0, wb1, wb2, wb3);

    gemm_bt<<<dim3(MTOT / 128, DMODEL / 128, 3), 256, 0, stream>>>(
        xb, wb0, wb1, wb2, q, k, vt, MTOT, DMODEL, DMODEL);
    attention<<<512, 512, 0, stream>>>(q, k, vt, ctx);
    gemm_bt_f32<<<dim3(MTOT / 128, DMODEL / 128, 1), 256, 0, stream>>>(
        ctx, wb3, out, MTOT, DMODEL, DMODEL);
}